// Round 22
// baseline (197.219 us; speedup 1.0000x reference)
//
#include <hip/hip_runtime.h>

typedef unsigned short u16;
typedef __bf16 bf16x8 __attribute__((ext_vector_type(8)));
typedef float f32x4 __attribute__((ext_vector_type(4)));
typedef u16 u16x8 __attribute__((ext_vector_type(8)));

#define B_ 4
#define S_ 2048
#define D_ 1024
#define H_ 16
#define LOG2E 1.44269504f

__device__ inline u16 f2bf(float f) {
  unsigned u = __float_as_uint(f);
  u = u + 0x7fffu + ((u >> 16) & 1u);
  return (u16)(u >> 16);
}
__device__ inline u16 f2bf_hw(float f) {
  __bf16 b = (__bf16)f;
  return __builtin_bit_cast(u16, b);
}
__device__ inline float bf2f(u16 h) {
  return __uint_as_float(((unsigned)h) << 16);
}
__device__ inline void gload_lds16(const u16* g, u16* l) {
  __builtin_amdgcn_global_load_lds((const __attribute__((address_space(1))) void*)g,
                                   (__attribute__((address_space(3))) void*)l, 16, 0, 0);
}
// raw HW exp2: one TRANS op, no libm denormal fix-up (inputs bounded).
__device__ inline float fast_exp2(float x) {
  float r;
  asm("v_exp_f32 %0, %1" : "=v"(r) : "v"(x));
  return r;
}

// ---------------- merged prep: x convert | w4 convert | rope table -----------
__global__ __launch_bounds__(256) void k_prep(const float* __restrict__ x,
                                              const float* __restrict__ w0,
                                              const float* __restrict__ w1,
                                              const float* __restrict__ w2,
                                              const float* __restrict__ w3,
                                              const int* __restrict__ pos,
                                              u16* __restrict__ xb,
                                              u16* __restrict__ wdst,
                                              float2* __restrict__ tab) {
  const int bid = blockIdx.x;
  if (bid < 8192) {                      // x: 2097152 float4 groups
    int i = bid * 256 + threadIdx.x;
    float4 v = reinterpret_cast<const float4*>(x)[i];
    ushort4 o;
    o.x = f2bf(v.x); o.y = f2bf(v.y); o.z = f2bf(v.z); o.w = f2bf(v.w);
    reinterpret_cast<ushort4*>(xb)[i] = o;
  } else if (bid < 12288) {              // weights: 4 x 262144 float4 groups
    int i = (bid - 8192) * 256 + threadIdx.x;
    const int tensor = i >> 18;
    const int local = i & 262143;
    const float* s = tensor == 0 ? w0 : tensor == 1 ? w1 : tensor == 2 ? w2 : w3;
    float4 v = reinterpret_cast<const float4*>(s)[local];
    ushort4 o;
    o.x = f2bf(v.x); o.y = f2bf(v.y); o.z = f2bf(v.z); o.w = f2bf(v.w);
    reinterpret_cast<ushort4*>(wdst + (size_t)tensor * 1048576)[local] = o;
  } else {                               // rope table: S*32 entries
    int idx = (bid - 12288) * 256 + threadIdx.x;
    int s = idx >> 5, i = idx & 31;
    float freq = powf(10000.0f, -(float)i * (1.0f / 32.0f));  // precise powf
    float ang = (float)pos[s] * freq;
    float sn, c;
    sincosf(ang, &sn, &c);
    tab[idx] = make_float2(c, sn);
  }
}

// ---------------- RoPE on K, in-place, vectorized (8 elems = 4 pairs/thread) -
__global__ __launch_bounds__(256) void k_rope_k(u16* __restrict__ kb,
                                                const float2* __restrict__ tab) {
  int idx = blockIdx.x * 256 + threadIdx.x;      // 1M threads
  const int row = idx >> 7;                      // 0..8191 (b*2048+s)
  const int s = row & 2047;
  const int chunk = idx & 127;                   // 8-elem chunk within row
  u16* p = kb + ((size_t)row << 10) + chunk * 8;
  u16x8 v = *reinterpret_cast<u16x8*>(p);
  const float4* tp = reinterpret_cast<const float4*>(tab + s * 32 + (chunk & 7) * 4);
  float4 t0 = tp[0], t1 = tp[1];
  float cc[4] = {t0.x, t0.z, t1.x, t1.z};
  float ss[4] = {t0.y, t0.w, t1.y, t1.w};
  u16x8 o;
#pragma unroll
  for (int u = 0; u < 4; u++) {
    float x1 = bf2f(v[2 * u]), x2 = bf2f(v[2 * u + 1]);
    o[2 * u]     = f2bf(x1 * cc[u] - x2 * ss[u]);
    o[2 * u + 1] = f2bf(x1 * ss[u] + x2 * cc[u]);
  }
  *reinterpret_cast<u16x8*>(p) = o;
}

// ---------------- Fused QKV GEMM v3: 128x256 tile, wave = 64x128 -------------
// Amortizes the measured fixed per-tile stall (~4000cyc period at 26% MfmaUtil)
// over 2x FLOP: 4 waves of 64x128 (acc[4][8]), single-buffer 48KB LDS (keeps
// 2 blocks/CU: regs ~200 -> 2 waves/SIMD anyway). Supertile window 8m x 4n
// (A 2MB + B 2MB = 4MB = per-XCD L2). Grid 768. V third -> vt layout.
__global__ __launch_bounds__(256) void k_gemm_qkv(const u16* __restrict__ A,
                                                  const u16* __restrict__ Bcat,
                                                  u16* __restrict__ Ccat,
                                                  u16* __restrict__ Vt) {
  __shared__ u16 As[128 * 64];
  __shared__ u16 Bs[256 * 64];
  const int K = 1024;
  const int xcd = blockIdx.x & 7;
  const int idx = blockIdx.x >> 3;               // 0..95
  const int win = idx >> 5;                      // 0..2 (4 n-tiles each)
  const int by = xcd * 8 + ((idx >> 2) & 7);     // m-tile 0..63
  const int bx = win * 4 + (idx & 3);            // n-tile 0..11
  const int m0 = by << 7, n0 = bx << 8;
  const int tid = threadIdx.x;
  const int lane = tid & 63;
  const int wv = tid >> 6;
  const int wm = (wv >> 1) << 6;                 // 0,64
  const int wn = (wv & 1) << 7;                  // 0,128
  const int r = lane & 15, g = lane >> 4;

  f32x4 acc[4][8] = {};

  const int srow0 = tid >> 3;                    // 0..31
  const int scol = (((tid & 7) ^ ((tid >> 3) & 7)) * 8);
  const int csw = r & 7;

  const u16* Ab = A + (size_t)(m0 + srow0) * K + scol;
  const u16* Bb = Bcat + (size_t)(n0 + srow0) * K + scol;

  for (int k0 = 0; k0 < K; k0 += 64) {
#pragma unroll
    for (int i = 0; i < 4; i++)
      gload_lds16(Ab + k0 + (size_t)(32 * i) * K, As + tid * 8 + i * 2048);
#pragma unroll
    for (int i = 0; i < 8; i++)
      gload_lds16(Bb + k0 + (size_t)(32 * i) * K, Bs + tid * 8 + i * 2048);
    __syncthreads();

#pragma unroll
    for (int ks = 0; ks < 2; ks++) {
      bf16x8 af[4], bfr[8];
#pragma unroll
      for (int i = 0; i < 4; i++)
        af[i] = *reinterpret_cast<const bf16x8*>(
            &As[(wm + i * 16 + r) * 64 + (((ks * 4 + g) ^ csw) * 8)]);
#pragma unroll
      for (int t2 = 0; t2 < 8; t2++)
        bfr[t2] = *reinterpret_cast<const bf16x8*>(
            &Bs[(wn + t2 * 16 + r) * 64 + (((ks * 4 + g) ^ csw) * 8)]);
#pragma unroll
      for (int i = 0; i < 4; i++)
#pragma unroll
        for (int t2 = 0; t2 < 8; t2++)
          acc[i][t2] = __builtin_amdgcn_mfma_f32_16x16x32_bf16(af[i], bfr[t2], acc[i][t2], 0, 0, 0);
    }
    __syncthreads();
  }

  const int bq = n0 >> 10;                 // 0=q, 1=k, 2=v (256 | 1024)
  const int c0 = n0 & 1023;
  if (bq == 2) {
    // V third -> vt[bh][d(64)][s(2048)]; j-values are consecutive s -> ushort4
#pragma unroll
    for (int i = 0; i < 4; i++) {
#pragma unroll
      for (int t = 0; t < 8; t++) {
        const int row = m0 + wm + i * 16 + g * 4;
        const int col = c0 + wn + t * 16 + r;
        const int b = row >> 11, s0 = row & 2047;
        const int h = col >> 6, d = col & 63;
        ushort4 o;
        o.x = f2bf(acc[i][t][0]); o.y = f2bf(acc[i][t][1]);
        o.z = f2bf(acc[i][t][2]); o.w = f2bf(acc[i][t][3]);
        *reinterpret_cast<ushort4*>(
            Vt + (((size_t)(b * 16 + h) * 64 + d) << 11) + s0) = o;
      }
    }
  } else {
    u16* Cb = Ccat + (size_t)bq * (8192 * 1024);
#pragma unroll
    for (int i = 0; i < 4; i++) {
#pragma unroll
      for (int t = 0; t < 8; t++) {
        const int row = m0 + wm + i * 16 + g * 4;
        const int col = c0 + wn + t * 16 + r;
#pragma unroll
        for (int j = 0; j < 4; j++)
          Cb[(size_t)(row + j) * 1024 + col] = f2bf(acc[i][t][j]);
      }
    }
  }
}

// ---------------- GEMM (f32 out, for Wo): BK=64 swizzled + dbuf --------------
__global__ __launch_bounds__(256) void k_gemm_bt(const u16* __restrict__ A,
                                                 const u16* __restrict__ Bw,
                                                 float* __restrict__ C,
                                                 int M, int N, int K) {
  __shared__ u16 As[2][128 * 64];
  __shared__ u16 Bs[2][128 * 64];
  const int nbx = N >> 7;
  const int swz = (blockIdx.x & 7) * (gridDim.x >> 3) + (blockIdx.x >> 3);
  const int bx = swz % nbx;
  const int by = swz / nbx;
  const int m0 = by << 7, n0 = bx << 7;
  const int tid = threadIdx.x;
  const int lane = tid & 63;
  const int wv = tid >> 6;
  const int wm = (wv >> 1) << 6;
  const int wn = (wv & 1) << 6;
  const int r = lane & 15, g = lane >> 4;

  f32x4 acc[4][4] = {};

  const int srow0 = tid >> 3;
  const int scol = (((tid & 7) ^ ((tid >> 3) & 7)) * 8);
  const int csw = r & 7;

  const u16* Ab = A + (size_t)(m0 + srow0) * K + scol;
  const u16* Bb = Bw + (size_t)(n0 + srow0) * K + scol;
  const int nt = K >> 6;

#define STAGEW(k0v, bf) do {                                       \
    const u16* a_ = Ab + (k0v);                                    \
    const u16* b_ = Bb + (k0v);                                    \
    gload_lds16(a_,                &As[bf][0] + tid * 8);          \
    gload_lds16(a_ + (size_t)32 * K, &As[bf][0] + tid * 8 + 2048); \
    gload_lds16(a_ + (size_t)64 * K, &As[bf][0] + tid * 8 + 4096); \
    gload_lds16(a_ + (size_t)96 * K, &As[bf][0] + tid * 8 + 6144); \
    gload_lds16(b_,                &Bs[bf][0] + tid * 8);          \
    gload_lds16(b_ + (size_t)32 * K, &Bs[bf][0] + tid * 8 + 2048); \
    gload_lds16(b_ + (size_t)64 * K, &Bs[bf][0] + tid * 8 + 4096); \
    gload_lds16(b_ + (size_t)96 * K, &Bs[bf][0] + tid * 8 + 6144); \
  } while (0)

  STAGEW(0, 0);

  for (int t = 0; t < nt; ++t) {
    const int bsel = t & 1;
    if (t < nt - 1) {
      STAGEW((t + 1) * 64, bsel ^ 1);
      asm volatile("s_waitcnt vmcnt(8)" ::: "memory");
    } else {
      asm volatile("s_waitcnt vmcnt(0)" ::: "memory");
    }
    __builtin_amdgcn_s_barrier();
    asm volatile("" ::: "memory");

#pragma unroll
    for (int ks = 0; ks < 2; ks++) {
      bf16x8 af[4], bfr[4];
#pragma unroll
      for (int i = 0; i < 4; i++)
        af[i] = *reinterpret_cast<const bf16x8*>(
            &As[bsel][(wm + i * 16 + r) * 64 + (((ks * 4 + g) ^ csw) * 8)]);
#pragma unroll
      for (int t2 = 0; t2 < 4; t2++)
        bfr[t2] = *reinterpret_cast<const bf16x8*>(
            &Bs[bsel][(wn + t2 * 16 + r) * 64 + (((ks * 4 + g) ^ csw) * 8)]);
#pragma unroll
      for (int i = 0; i < 4; i++)
#pragma unroll
        for (int t2 = 0; t2 < 4; t2++)
          acc[i][t2] = __builtin_amdgcn_mfma_f32_16x16x32_bf16(af[i], bfr[t2], acc[i][t2], 0, 0, 0);
    }
    asm volatile("" ::: "memory");
    __builtin_amdgcn_s_barrier();
  }
#undef STAGEW

#pragma unroll
  for (int i = 0; i < 4; i++) {
#pragma unroll
    for (int t = 0; t < 4; t++) {
      const int row = m0 + wm + i * 16 + g * 4;
      const int col = n0 + wn + t * 16 + r;
#pragma unroll
      for (int j = 0; j < 4; j++)
        C[(size_t)(row + j) * N + col] = acc[i][t][j];
    }
  }
}

// ---------------- Flash attention v14 (measured-best) ------------------------
// fast_exp2 softmax; MFMA row-sum l; in-register Q-RoPE; single-buffer LDS.
__global__ __launch_bounds__(256) void k_attn14(const u16* __restrict__ Q,
                                                const u16* __restrict__ Kb,
                                                const u16* __restrict__ Vt,
                                                const float2* __restrict__ tab,
                                                u16* __restrict__ O) {
  __shared__ u16 Ks[64 * 64];       // [k(64)][d(64)] swizzled
  __shared__ u16 Vs[64 * 64];       // [d(64)][kv(64)] swizzled
  __shared__ u16 Ps[4][32 * 64];    // per-wave [q(32)][k(64)] swizzled

  const int bh = (blockIdx.x & 7) * 8 + ((blockIdx.x >> 3) & 7);
  const int qt = 15 - (blockIdx.x >> 6);
  const int b = bh >> 4, h = bh & 15;
  const int tid = threadIdx.x;
  const int lane = tid & 63, w = tid >> 6;
  const int g = lane >> 4, r = lane & 15;

  const u16* Kbase = Kb + (size_t)(b * S_) * 1024 + h * 64;
  const u16* Vbase = Vt + (size_t)bh * 64 * 2048;

  const int srow = tid >> 3;
  const int scol = ((tid & 7) * 8) ^ ((srow & 7) * 8);
  const int rsw = (r & 7) * 8;

  const int qbase = qt << 7;
  const int qrow0 = qbase + (w << 5);

  const float QSC = 0.125f * LOG2E;
  bf16x8 qf[2][2];
#pragma unroll
  for (int f = 0; f < 2; f++) {
    const int s = qrow0 + f * 16 + r;
    const u16* qrow = Q + (size_t)(b * S_ + s) * 1024 + h * 64;
    qf[f][0] = *reinterpret_cast<const bf16x8*>(qrow + g * 8);
    qf[f][1] = *reinterpret_cast<const bf16x8*>(qrow + 32 + g * 8);
    const float4* tp = reinterpret_cast<const float4*>(tab + s * 32);
#pragma unroll
    for (int c = 0; c < 2; c++) {
      float4 t0 = tp[c * 8 + g * 2], t1 = tp[c * 8 + g * 2 + 1];
      float cc[4] = {t0.x, t0.z, t1.x, t1.z};
      float ss[4] = {t0.y, t0.w, t1.y, t1.w};
      bf16x8 q = qf[f][c];
#pragma unroll
      for (int u = 0; u < 4; u++) {
        float x1 = (float)q[2 * u], x2 = (float)q[2 * u + 1];
        q[2 * u]     = (__bf16)((x1 * cc[u] - x2 * ss[u]) * QSC);
        q[2 * u + 1] = (__bf16)((x1 * ss[u] + x2 * cc[u]) * QSC);
      }
      qf[f][c] = q;
    }
  }

  // all-ones B fragment (layout-independent: every element 1.0bf16)
  bf16x8 ones;
#pragma unroll
  for (int u = 0; u < 8; u++) ones[u] = (__bf16)1.0f;

  f32x4 o_acc[2][4] = {};
  f32x4 lacc[2] = {};                  // MFMA row-sum accumulators
  u16* pb0 = &Ps[w][r * 64];
  u16* pb1 = &Ps[w][(16 + r) * 64];

  const u16* kp0 = Kbase + (size_t)srow * 1024 + scol;
  const u16* kp1 = kp0 + 32 * 1024;
  const u16* vp0 = Vbase + (size_t)srow * 2048 + scol;
  const u16* vp1 = vp0 + 32 * 2048;

  const int kend = qbase + 128;
  for (int k0 = 0; k0 < kend; k0 += 64) {
    gload_lds16(kp0, Ks + tid * 8);
    gload_lds16(kp1, Ks + tid * 8 + 2048);
    gload_lds16(vp0, Vs + tid * 8);
    gload_lds16(vp1, Vs + tid * 8 + 2048);
    kp0 += 64 * 1024; kp1 += 64 * 1024; vp0 += 64; vp1 += 64;
    __syncthreads();

    if (k0 <= qrow0 + 31) {
      const int rem0 = qrow0 + 15 - k0;
      const int rem1 = qrow0 + 31 - k0;
      const int ktlim0 = rem0 < 0 ? 0 : (rem0 >= 48 ? 4 : (rem0 >> 4) + 1);
      const int ktlim1 = rem1 >= 48 ? 4 : (rem1 >> 4) + 1;
      const bool mask0 = (k0 + 63 > qrow0);
      const bool mask1 = (k0 + 63 > qrow0 + 16);

#pragma unroll
      for (int kt = 0; kt < 4; kt++) {
        const int pc = (kt * 16 + g * 4) ^ rsw;
        if (kt >= ktlim1) {
          ushort4 z = {0, 0, 0, 0};
          *reinterpret_cast<ushort4*>(pb0 + pc) = z;
          *reinterpret_cast<ushort4*>(pb1 + pc) = z;
          continue;
        }
        const int krow = kt * 16 + r;
        bf16x8 kf0 = *reinterpret_cast<const bf16x8*>(&Ks[krow * 64 + ((g * 8) ^ rsw)]);
        bf16x8 kf1 = *reinterpret_cast<const bf16x8*>(&Ks[krow * 64 + ((32 + g * 8) ^ rsw)]);
        f32x4 s0 = {}, s1 = {};
        if (kt < ktlim0) {
          s0 = __builtin_amdgcn_mfma_f32_16x16x32_bf16(kf0, qf[0][0], s0, 0, 0, 0);
          s0 = __builtin_amdgcn_mfma_f32_16x16x32_bf16(kf1, qf[0][1], s0, 0, 0, 0);
        }
        s1 = __builtin_amdgcn_mfma_f32_16x16x32_bf16(kf0, qf[1][0], s1, 0, 0, 0);
        s1 = __builtin_amdgcn_mfma_f32_16x16x32_bf16(kf1, qf[1][1], s1, 0, 0, 0);

        const int colb = k0 + kt * 16 + g * 4;
        float p0[4], p1[4];
        if (kt < ktlim0) {
          if (mask0) {
#pragma unroll
            for (int j = 0; j < 4; j++)
              if (colb + j > qrow0 + r) s0[j] = -1e30f;
          }
#pragma unroll
          for (int j = 0; j < 4; j++) p0[j] = fast_exp2(s0[j]);
        } else {
#pragma unroll
          for (int j = 0; j < 4; j++) p0[j] = 0.f;
        }
        if (mask1) {
#pragma unroll
          for (int j = 0; j < 4; j++)
            if (colb + j > qrow0 + 16 + r) s1[j] = -1e30f;
        }
#pragma unroll
        for (int j = 0; j < 4; j++) p1[j] = fast_exp2(s1[j]);

        ushort4 w0, w1;
        w0.x = f2bf_hw(p0[0]); w0.y = f2bf_hw(p0[1]); w0.z = f2bf_hw(p0[2]); w0.w = f2bf_hw(p0[3]);
        w1.x = f2bf_hw(p1[0]); w1.y = f2bf_hw(p1[1]); w1.z = f2bf_hw(p1[2]); w1.w = f2bf_hw(p1[3]);
        *reinterpret_cast<ushort4*>(pb0 + pc) = w0;
        *reinterpret_cast<ushort4*>(pb1 + pc) = w1;
      }
      asm volatile("s_waitcnt lgkmcnt(0)" ::: "memory");

      // ---- PV + MFMA row-sum of P (l) ----
#pragma unroll
      for (int kc = 0; kc < 2; kc++) {
        const int cb = (kc * 32 + g * 8) ^ rsw;
        bf16x8 pf0 = *reinterpret_cast<const bf16x8*>(pb0 + cb);
        bf16x8 pf1 = *reinterpret_cast<const bf16x8*>(pb1 + cb);
        lacc[0] = __builtin_amdgcn_mfma_f32_16x16x32_bf16(pf0, ones, lacc[0], 0, 0, 0);
        lacc[1] = __builtin_amdgcn_mfma_f32_16x16x32_bf16(pf1, ones, lacc[1], 0, 0, 0);
#pragma unroll
        for (int dt = 0; dt < 4; dt++) {
          bf16x8 vf = *reinterpret_cast<const bf16x8*>(
              &Vs[(dt * 16 + r) * 64 + ((kc * 32 + g * 8) ^ rsw)]);
          o_acc[0][dt] = __builtin_amdgcn_mfma_f32_16x16x32_bf16(pf0, vf, o_acc[0][dt], 0, 0, 0);
          o_acc[1][dt] = __builtin_amdgcn_mfma_f32_16x16x32_bf16(pf1, vf, o_acc[1][dt], 0, 0, 0);
        }
      }
    }
    __syncthreads();
  }

  // ---- epilogue: lacc[f][j] IS l for output row g*4+j (no shuffles) ----
#pragma unroll
  for (int f = 0; f < 2; f++) {
    u16* orow = O + (size_t)(b * S_ + qrow0 + f * 16) * 1024 + h * 64;
#pragma unroll
    for (int j = 0; j < 4; j++) {
      const float rln = 1.0f / lacc[f][j];
#pragma unroll
      for (int dt = 0; dt < 4; dt++)
        orow[(size_t)(g * 4 + j) * 1024 + dt * 16 + r] = f2bf(o_acc[f][dt][j] * rln);
    }
  }
}

// ---------------- host side ----------------
extern "C" void kernel_launch(void* const* d_in, const int* in_sizes, int n_in,
                              void* d_out, int out_size, void* d_ws, size_t ws_size,
                              hipStream_t stream) {
  const float* x  = (const float*)d_in[0];
  const int*   pos = (const int*)d_in[1];
  const float* Wq = (const float*)d_in[2];
  const float* Wk = (const float*)d_in[3];
  const float* Wv = (const float*)d_in[4];
  const float* Wo = (const float*)d_in[5];
  float* out = (float*)d_out;

  char* ws = (char*)d_ws;
  size_t off = 0;
  auto alloc = [&](size_t bytes) {
    void* p = ws + off;
    off += (bytes + 255) & ~(size_t)255;
    return p;
  };
  const size_t XB = (size_t)8192 * 1024 * 2;  // bf16 [B*S][D]
  u16* xb  = (u16*)alloc(XB);
  u16* wqb = (u16*)alloc((size_t)1024 * 1024 * 2);   // contiguous ->
  u16* wkb = (u16*)alloc((size_t)1024 * 1024 * 2);   //   Wcat[3072][1024] + wo
  u16* wvb = (u16*)alloc((size_t)1024 * 1024 * 2);
  u16* wob = (u16*)alloc((size_t)1024 * 1024 * 2);
  u16* qb  = (u16*)alloc(XB);                        // contiguous: q|k
  u16* kb  = (u16*)alloc(XB);
  u16* ob  = (u16*)alloc(XB);
  u16* vt  = (u16*)alloc(XB);
  float2* tab = (float2*)alloc((size_t)2048 * 32 * sizeof(float2));
  (void)wkb; (void)wvb;

  // merged prep: x convert + weight converts + rope table (one dispatch)
  k_prep<<<12544, 256, 0, stream>>>(x, Wq, Wk, Wv, Wo, pos, xb, wqb, tab);

  // fused QKV projection v3: 128x256 tiles, wave 64x128; V -> vt layout
  k_gemm_qkv<<<768, 256, 0, stream>>>(xb, wqb, qb, vt);

  // RoPE on K (in-place, vectorized); Q's RoPE happens inside attn
  k_rope_k<<<4096, 256, 0, stream>>>(kb, tab);

  // flash attention v14: 64 bh x 16 q-tiles of 128 rows, heavy-first
  k_attn14<<<1024, 256, 0, stream>>>(qb, kb, vt, tab, ob);

  // output projection -> f32 out, BK=64 swizzled, dbuf
  k_gemm_bt<<<512, 256, 0, stream>>>(ob, wob, out, 8192, 1024, 1024);
}

// Round 23
// 172.256 us; speedup vs baseline: 1.1449x; 1.1449x over previous
//
#include <hip/hip_runtime.h>

typedef unsigned short u16;
typedef __bf16 bf16x8 __attribute__((ext_vector_type(8)));
typedef float f32x4 __attribute__((ext_vector_type(4)));
typedef u16 u16x8 __attribute__((ext_vector_type(8)));

#define B_ 4
#define S_ 2048
#define D_ 1024
#define H_ 16
#define LOG2E 1.44269504f

__device__ inline u16 f2bf(float f) {
  unsigned u = __float_as_uint(f);
  u = u + 0x7fffu + ((u >> 16) & 1u);
  return (u16)(u >> 16);
}
__device__ inline u16 f2bf_hw(float f) {
  __bf16 b = (__bf16)f;
  return __builtin_bit_cast(u16, b);
}
__device__ inline float bf2f(u16 h) {
  return __uint_as_float(((unsigned)h) << 16);
}
__device__ inline void gload_lds16(const u16* g, u16* l) {
  __builtin_amdgcn_global_load_lds((const __attribute__((address_space(1))) void*)g,
                                   (__attribute__((address_space(3))) void*)l, 16, 0, 0);
}
// raw HW exp2: one TRANS op, no libm denormal fix-up (inputs bounded).
__device__ inline float fast_exp2(float x) {
  float r;
  asm("v_exp_f32 %0, %1" : "=v"(r) : "v"(x));
  return r;
}

// ---------------- merged prep: x convert | w4 convert | rope table -----------
__global__ __launch_bounds__(256) void k_prep(const float* __restrict__ x,
                                              const float* __restrict__ w0,
                                              const float* __restrict__ w1,
                                              const float* __restrict__ w2,
                                              const float* __restrict__ w3,
                                              const int* __restrict__ pos,
                                              u16* __restrict__ xb,
                                              u16* __restrict__ wdst,
                                              float2* __restrict__ tab) {
  const int bid = blockIdx.x;
  if (bid < 8192) {                      // x: 2097152 float4 groups
    int i = bid * 256 + threadIdx.x;
    float4 v = reinterpret_cast<const float4*>(x)[i];
    ushort4 o;
    o.x = f2bf(v.x); o.y = f2bf(v.y); o.z = f2bf(v.z); o.w = f2bf(v.w);
    reinterpret_cast<ushort4*>(xb)[i] = o;
  } else if (bid < 12288) {              // weights: 4 x 262144 float4 groups
    int i = (bid - 8192) * 256 + threadIdx.x;
    const int tensor = i >> 18;
    const int local = i & 262143;
    const float* s = tensor == 0 ? w0 : tensor == 1 ? w1 : tensor == 2 ? w2 : w3;
    float4 v = reinterpret_cast<const float4*>(s)[local];
    ushort4 o;
    o.x = f2bf(v.x); o.y = f2bf(v.y); o.z = f2bf(v.z); o.w = f2bf(v.w);
    reinterpret_cast<ushort4*>(wdst + (size_t)tensor * 1048576)[local] = o;
  } else {                               // rope table: S*32 entries
    int idx = (bid - 12288) * 256 + threadIdx.x;
    int s = idx >> 5, i = idx & 31;
    float freq = powf(10000.0f, -(float)i * (1.0f / 32.0f));  // precise powf
    float ang = (float)pos[s] * freq;
    float sn, c;
    sincosf(ang, &sn, &c);
    tab[idx] = make_float2(c, sn);
  }
}

// ---------------- RoPE on K, in-place, vectorized (8 elems = 4 pairs/thread) -
__global__ __launch_bounds__(256) void k_rope_k(u16* __restrict__ kb,
                                                const float2* __restrict__ tab) {
  int idx = blockIdx.x * 256 + threadIdx.x;      // 1M threads
  const int row = idx >> 7;                      // 0..8191 (b*2048+s)
  const int s = row & 2047;
  const int chunk = idx & 127;                   // 8-elem chunk within row
  u16* p = kb + ((size_t)row << 10) + chunk * 8;
  u16x8 v = *reinterpret_cast<u16x8*>(p);
  const float4* tp = reinterpret_cast<const float4*>(tab + s * 32 + (chunk & 7) * 4);
  float4 t0 = tp[0], t1 = tp[1];
  float cc[4] = {t0.x, t0.z, t1.x, t1.z};
  float ss[4] = {t0.y, t0.w, t1.y, t1.w};
  u16x8 o;
#pragma unroll
  for (int u = 0; u < 4; u++) {
    float x1 = bf2f(v[2 * u]), x2 = bf2f(v[2 * u + 1]);
    o[2 * u]     = f2bf(x1 * cc[u] - x2 * ss[u]);
    o[2 * u + 1] = f2bf(x1 * ss[u] + x2 * cc[u]);
  }
  *reinterpret_cast<u16x8*>(p) = o;
}

// ---------------- Fused QKV GEMM: BK=64 swizzled + dbuf + counted vmcnt ------
// L2-supertile block mapping (8m x 8n window = 4MB = per-XCD L2): FETCH 49MB.
__global__ __launch_bounds__(256) void k_gemm_qkv(const u16* __restrict__ A,
                                                  const u16* __restrict__ Bcat,
                                                  u16* __restrict__ Ccat,
                                                  u16* __restrict__ Vt) {
  __shared__ u16 As[2][128 * 64];
  __shared__ u16 Bs[2][128 * 64];
  const int K = 1024;
  const int xcd = blockIdx.x & 7;
  const int idx = blockIdx.x >> 3;               // 0..191
  const int st = idx >> 6;                       // 0..2 supertile col (8 n each)
  const int mi = (idx & 63) >> 3;                // 0..7
  const int ni = idx & 7;                        // 0..7
  const int by = xcd * 8 + mi;                   // m-tile 0..63
  const int bx = st * 8 + ni;                    // n-tile 0..23
  const int m0 = by << 7, n0 = bx << 7;
  const int tid = threadIdx.x;
  const int lane = tid & 63;
  const int wv = tid >> 6;
  const int wm = (wv >> 1) << 6;
  const int wn = (wv & 1) << 6;
  const int r = lane & 15, g = lane >> 4;

  f32x4 acc[4][4] = {};

  const int srow0 = tid >> 3;
  const int scol = (((tid & 7) ^ ((tid >> 3) & 7)) * 8);
  const int csw = r & 7;

  const u16* Ab = A + (size_t)(m0 + srow0) * K + scol;
  const u16* Bb = Bcat + (size_t)(n0 + srow0) * K + scol;

#define STAGEQ(k0v, bf) do {                                       \
    const u16* a_ = Ab + (k0v);                                    \
    const u16* b_ = Bb + (k0v);                                    \
    gload_lds16(a_,                &As[bf][0] + tid * 8);          \
    gload_lds16(a_ + (size_t)32 * K, &As[bf][0] + tid * 8 + 2048); \
    gload_lds16(a_ + (size_t)64 * K, &As[bf][0] + tid * 8 + 4096); \
    gload_lds16(a_ + (size_t)96 * K, &As[bf][0] + tid * 8 + 6144); \
    gload_lds16(b_,                &Bs[bf][0] + tid * 8);          \
    gload_lds16(b_ + (size_t)32 * K, &Bs[bf][0] + tid * 8 + 2048); \
    gload_lds16(b_ + (size_t)64 * K, &Bs[bf][0] + tid * 8 + 4096); \
    gload_lds16(b_ + (size_t)96 * K, &Bs[bf][0] + tid * 8 + 6144); \
  } while (0)

  STAGEQ(0, 0);

  for (int t = 0; t < 16; ++t) {
    const int bsel = t & 1;
    if (t < 15) {
      STAGEQ((t + 1) * 64, bsel ^ 1);
      asm volatile("s_waitcnt vmcnt(8)" ::: "memory");   // current tile landed
    } else {
      asm volatile("s_waitcnt vmcnt(0)" ::: "memory");
    }
    __builtin_amdgcn_s_barrier();
    asm volatile("" ::: "memory");

#pragma unroll
    for (int ks = 0; ks < 2; ks++) {
      bf16x8 af[4], bfr[4];
#pragma unroll
      for (int i = 0; i < 4; i++)
        af[i] = *reinterpret_cast<const bf16x8*>(
            &As[bsel][(wm + i * 16 + r) * 64 + (((ks * 4 + g) ^ csw) * 8)]);
#pragma unroll
      for (int t2 = 0; t2 < 4; t2++)
        bfr[t2] = *reinterpret_cast<const bf16x8*>(
            &Bs[bsel][(wn + t2 * 16 + r) * 64 + (((ks * 4 + g) ^ csw) * 8)]);
#pragma unroll
      for (int i = 0; i < 4; i++)
#pragma unroll
        for (int t2 = 0; t2 < 4; t2++)
          acc[i][t2] = __builtin_amdgcn_mfma_f32_16x16x32_bf16(af[i], bfr[t2], acc[i][t2], 0, 0, 0);
    }
    asm volatile("" ::: "memory");
    __builtin_amdgcn_s_barrier();                        // reads of bsel done
  }
#undef STAGEQ

  const int bq = n0 >> 10;                 // 0=q, 1=k, 2=v
  const int c0 = n0 & 1023;
  if (bq == 2) {
    // V third -> vt[bh][d(64)][s(2048)]; j-values are consecutive s -> ushort4
#pragma unroll
    for (int i = 0; i < 4; i++) {
#pragma unroll
      for (int t = 0; t < 4; t++) {
        const int row = m0 + wm + i * 16 + g * 4;
        const int col = c0 + wn + t * 16 + r;
        const int b = row >> 11, s0 = row & 2047;
        const int h = col >> 6, d = col & 63;
        ushort4 o;
        o.x = f2bf(acc[i][t][0]); o.y = f2bf(acc[i][t][1]);
        o.z = f2bf(acc[i][t][2]); o.w = f2bf(acc[i][t][3]);
        *reinterpret_cast<ushort4*>(
            Vt + (((size_t)(b * 16 + h) * 64 + d) << 11) + s0) = o;
      }
    }
  } else {
    u16* Cb = Ccat + (size_t)bq * (8192 * 1024);
#pragma unroll
    for (int i = 0; i < 4; i++) {
#pragma unroll
      for (int t = 0; t < 4; t++) {
        const int row = m0 + wm + i * 16 + g * 4;
        const int col = c0 + wn + t * 16 + r;
#pragma unroll
        for (int j = 0; j < 4; j++)
          Cb[(size_t)(row + j) * 1024 + col] = f2bf(acc[i][t][j]);
      }
    }
  }
}

// ---------------- GEMM (f32 out, for Wo): BK=64 swizzled + dbuf --------------
__global__ __launch_bounds__(256) void k_gemm_bt(const u16* __restrict__ A,
                                                 const u16* __restrict__ Bw,
                                                 float* __restrict__ C,
                                                 int M, int N, int K) {
  __shared__ u16 As[2][128 * 64];
  __shared__ u16 Bs[2][128 * 64];
  const int nbx = N >> 7;
  const int swz = (blockIdx.x & 7) * (gridDim.x >> 3) + (blockIdx.x >> 3);
  const int bx = swz % nbx;
  const int by = swz / nbx;
  const int m0 = by << 7, n0 = bx << 7;
  const int tid = threadIdx.x;
  const int lane = tid & 63;
  const int wv = tid >> 6;
  const int wm = (wv >> 1) << 6;
  const int wn = (wv & 1) << 6;
  const int r = lane & 15, g = lane >> 4;

  f32x4 acc[4][4] = {};

  const int srow0 = tid >> 3;
  const int scol = (((tid & 7) ^ ((tid >> 3) & 7)) * 8);
  const int csw = r & 7;

  const u16* Ab = A + (size_t)(m0 + srow0) * K + scol;
  const u16* Bb = Bw + (size_t)(n0 + srow0) * K + scol;
  const int nt = K >> 6;

#define STAGEW(k0v, bf) do {                                       \
    const u16* a_ = Ab + (k0v);                                    \
    const u16* b_ = Bb + (k0v);                                    \
    gload_lds16(a_,                &As[bf][0] + tid * 8);          \
    gload_lds16(a_ + (size_t)32 * K, &As[bf][0] + tid * 8 + 2048); \
    gload_lds16(a_ + (size_t)64 * K, &As[bf][0] + tid * 8 + 4096); \
    gload_lds16(a_ + (size_t)96 * K, &As[bf][0] + tid * 8 + 6144); \
    gload_lds16(b_,                &Bs[bf][0] + tid * 8);          \
    gload_lds16(b_ + (size_t)32 * K, &Bs[bf][0] + tid * 8 + 2048); \
    gload_lds16(b_ + (size_t)64 * K, &Bs[bf][0] + tid * 8 + 4096); \
    gload_lds16(b_ + (size_t)96 * K, &Bs[bf][0] + tid * 8 + 6144); \
  } while (0)

  STAGEW(0, 0);

  for (int t = 0; t < nt; ++t) {
    const int bsel = t & 1;
    if (t < nt - 1) {
      STAGEW((t + 1) * 64, bsel ^ 1);
      asm volatile("s_waitcnt vmcnt(8)" ::: "memory");
    } else {
      asm volatile("s_waitcnt vmcnt(0)" ::: "memory");
    }
    __builtin_amdgcn_s_barrier();
    asm volatile("" ::: "memory");

#pragma unroll
    for (int ks = 0; ks < 2; ks++) {
      bf16x8 af[4], bfr[4];
#pragma unroll
      for (int i = 0; i < 4; i++)
        af[i] = *reinterpret_cast<const bf16x8*>(
            &As[bsel][(wm + i * 16 + r) * 64 + (((ks * 4 + g) ^ csw) * 8)]);
#pragma unroll
      for (int t2 = 0; t2 < 4; t2++)
        bfr[t2] = *reinterpret_cast<const bf16x8*>(
            &Bs[bsel][(wn + t2 * 16 + r) * 64 + (((ks * 4 + g) ^ csw) * 8)]);
#pragma unroll
      for (int i = 0; i < 4; i++)
#pragma unroll
        for (int t2 = 0; t2 < 4; t2++)
          acc[i][t2] = __builtin_amdgcn_mfma_f32_16x16x32_bf16(af[i], bfr[t2], acc[i][t2], 0, 0, 0);
    }
    asm volatile("" ::: "memory");
    __builtin_amdgcn_s_barrier();
  }
#undef STAGEW

#pragma unroll
  for (int i = 0; i < 4; i++) {
#pragma unroll
    for (int t = 0; t < 4; t++) {
      const int row = m0 + wm + i * 16 + g * 4;
      const int col = n0 + wn + t * 16 + r;
#pragma unroll
      for (int j = 0; j < 4; j++)
        C[(size_t)(row + j) * N + col] = acc[i][t][j];
    }
  }
}

// ---------------- Flash attention v14 (measured-best) ------------------------
// fast_exp2 softmax; MFMA row-sum l; in-register Q-RoPE; single-buffer LDS.
__global__ __launch_bounds__(256) void k_attn14(const u16* __restrict__ Q,
                                                const u16* __restrict__ Kb,
                                                const u16* __restrict__ Vt,
                                                const float2* __restrict__ tab,
                                                u16* __restrict__ O) {
  __shared__ u16 Ks[64 * 64];       // [k(64)][d(64)] swizzled
  __shared__ u16 Vs[64 * 64];       // [d(64)][kv(64)] swizzled
  __shared__ u16 Ps[4][32 * 64];    // per-wave [q(32)][k(64)] swizzled

  const int bh = (blockIdx.x & 7) * 8 + ((blockIdx.x >> 3) & 7);
  const int qt = 15 - (blockIdx.x >> 6);
  const int b = bh >> 4, h = bh & 15;
  const int tid = threadIdx.x;
  const int lane = tid & 63, w = tid >> 6;
  const int g = lane >> 4, r = lane & 15;

  const u16* Kbase = Kb + (size_t)(b * S_) * 1024 + h * 64;
  const u16* Vbase = Vt + (size_t)bh * 64 * 2048;

  const int srow = tid >> 3;
  const int scol = ((tid & 7) * 8) ^ ((srow & 7) * 8);
  const int rsw = (r & 7) * 8;

  const int qbase = qt << 7;
  const int qrow0 = qbase + (w << 5);

  const float QSC = 0.125f * LOG2E;
  bf16x8 qf[2][2];
#pragma unroll
  for (int f = 0; f < 2; f++) {
    const int s = qrow0 + f * 16 + r;
    const u16* qrow = Q + (size_t)(b * S_ + s) * 1024 + h * 64;
    qf[f][0] = *reinterpret_cast<const bf16x8*>(qrow + g * 8);
    qf[f][1] = *reinterpret_cast<const bf16x8*>(qrow + 32 + g * 8);
    const float4* tp = reinterpret_cast<const float4*>(tab + s * 32);
#pragma unroll
    for (int c = 0; c < 2; c++) {
      float4 t0 = tp[c * 8 + g * 2], t1 = tp[c * 8 + g * 2 + 1];
      float cc[4] = {t0.x, t0.z, t1.x, t1.z};
      float ss[4] = {t0.y, t0.w, t1.y, t1.w};
      bf16x8 q = qf[f][c];
#pragma unroll
      for (int u = 0; u < 4; u++) {
        float x1 = (float)q[2 * u], x2 = (float)q[2 * u + 1];
        q[2 * u]     = (__bf16)((x1 * cc[u] - x2 * ss[u]) * QSC);
        q[2 * u + 1] = (__bf16)((x1 * ss[u] + x2 * cc[u]) * QSC);
      }
      qf[f][c] = q;
    }
  }

  // all-ones B fragment (layout-independent: every element 1.0bf16)
  bf16x8 ones;
#pragma unroll
  for (int u = 0; u < 8; u++) ones[u] = (__bf16)1.0f;

  f32x4 o_acc[2][4] = {};
  f32x4 lacc[2] = {};                  // MFMA row-sum accumulators
  u16* pb0 = &Ps[w][r * 64];
  u16* pb1 = &Ps[w][(16 + r) * 64];

  const u16* kp0 = Kbase + (size_t)srow * 1024 + scol;
  const u16* kp1 = kp0 + 32 * 1024;
  const u16* vp0 = Vbase + (size_t)srow * 2048 + scol;
  const u16* vp1 = vp0 + 32 * 2048;

  const int kend = qbase + 128;
  for (int k0 = 0; k0 < kend; k0 += 64) {
    gload_lds16(kp0, Ks + tid * 8);
    gload_lds16(kp1, Ks + tid * 8 + 2048);
    gload_lds16(vp0, Vs + tid * 8);
    gload_lds16(vp1, Vs + tid * 8 + 2048);
    kp0 += 64 * 1024; kp1 += 64 * 1024; vp0 += 64; vp1 += 64;
    __syncthreads();

    if (k0 <= qrow0 + 31) {
      const int rem0 = qrow0 + 15 - k0;
      const int rem1 = qrow0 + 31 - k0;
      const int ktlim0 = rem0 < 0 ? 0 : (rem0 >= 48 ? 4 : (rem0 >> 4) + 1);
      const int ktlim1 = rem1 >= 48 ? 4 : (rem1 >> 4) + 1;
      const bool mask0 = (k0 + 63 > qrow0);
      const bool mask1 = (k0 + 63 > qrow0 + 16);

#pragma unroll
      for (int kt = 0; kt < 4; kt++) {
        const int pc = (kt * 16 + g * 4) ^ rsw;
        if (kt >= ktlim1) {
          ushort4 z = {0, 0, 0, 0};
          *reinterpret_cast<ushort4*>(pb0 + pc) = z;
          *reinterpret_cast<ushort4*>(pb1 + pc) = z;
          continue;
        }
        const int krow = kt * 16 + r;
        bf16x8 kf0 = *reinterpret_cast<const bf16x8*>(&Ks[krow * 64 + ((g * 8) ^ rsw)]);
        bf16x8 kf1 = *reinterpret_cast<const bf16x8*>(&Ks[krow * 64 + ((32 + g * 8) ^ rsw)]);
        f32x4 s0 = {}, s1 = {};
        if (kt < ktlim0) {
          s0 = __builtin_amdgcn_mfma_f32_16x16x32_bf16(kf0, qf[0][0], s0, 0, 0, 0);
          s0 = __builtin_amdgcn_mfma_f32_16x16x32_bf16(kf1, qf[0][1], s0, 0, 0, 0);
        }
        s1 = __builtin_amdgcn_mfma_f32_16x16x32_bf16(kf0, qf[1][0], s1, 0, 0, 0);
        s1 = __builtin_amdgcn_mfma_f32_16x16x32_bf16(kf1, qf[1][1], s1, 0, 0, 0);

        const int colb = k0 + kt * 16 + g * 4;
        float p0[4], p1[4];
        if (kt < ktlim0) {
          if (mask0) {
#pragma unroll
            for (int j = 0; j < 4; j++)
              if (colb + j > qrow0 + r) s0[j] = -1e30f;
          }
#pragma unroll
          for (int j = 0; j < 4; j++) p0[j] = fast_exp2(s0[j]);
        } else {
#pragma unroll
          for (int j = 0; j < 4; j++) p0[j] = 0.f;
        }
        if (mask1) {
#pragma unroll
          for (int j = 0; j < 4; j++)
            if (colb + j > qrow0 + 16 + r) s1[j] = -1e30f;
        }
#pragma unroll
        for (int j = 0; j < 4; j++) p1[j] = fast_exp2(s1[j]);

        ushort4 w0, w1;
        w0.x = f2bf_hw(p0[0]); w0.y = f2bf_hw(p0[1]); w0.z = f2bf_hw(p0[2]); w0.w = f2bf_hw(p0[3]);
        w1.x = f2bf_hw(p1[0]); w1.y = f2bf_hw(p1[1]); w1.z = f2bf_hw(p1[2]); w1.w = f2bf_hw(p1[3]);
        *reinterpret_cast<ushort4*>(pb0 + pc) = w0;
        *reinterpret_cast<ushort4*>(pb1 + pc) = w1;
      }
      asm volatile("s_waitcnt lgkmcnt(0)" ::: "memory");

      // ---- PV + MFMA row-sum of P (l) ----
#pragma unroll
      for (int kc = 0; kc < 2; kc++) {
        const int cb = (kc * 32 + g * 8) ^ rsw;
        bf16x8 pf0 = *reinterpret_cast<const bf16x8*>(pb0 + cb);
        bf16x8 pf1 = *reinterpret_cast<const bf16x8*>(pb1 + cb);
        lacc[0] = __builtin_amdgcn_mfma_f32_16x16x32_bf16(pf0, ones, lacc[0], 0, 0, 0);
        lacc[1] = __builtin_amdgcn_mfma_f32_16x16x32_bf16(pf1, ones, lacc[1], 0, 0, 0);
#pragma unroll
        for (int dt = 0; dt < 4; dt++) {
          bf16x8 vf = *reinterpret_cast<const bf16x8*>(
              &Vs[(dt * 16 + r) * 64 + ((kc * 32 + g * 8) ^ rsw)]);
          o_acc[0][dt] = __builtin_amdgcn_mfma_f32_16x16x32_bf16(pf0, vf, o_acc[0][dt], 0, 0, 0);
          o_acc[1][dt] = __builtin_amdgcn_mfma_f32_16x16x32_bf16(pf1, vf, o_acc[1][dt], 0, 0, 0);
        }
      }
    }
    __syncthreads();
  }

  // ---- epilogue: lacc[f][j] IS l for output row g*4+j (no shuffles) ----
#pragma unroll
  for (int f = 0; f < 2; f++) {
    u16* orow = O + (size_t)(b * S_ + qrow0 + f * 16) * 1024 + h * 64;
#pragma unroll
    for (int j = 0; j < 4; j++) {
      const float rln = 1.0f / lacc[f][j];
#pragma unroll
      for (int dt = 0; dt < 4; dt++)
        orow[(size_t)(g * 4 + j) * 1024 + dt * 16 + r] = f2bf(o_acc[f][dt][j] * rln);
    }
  }
}

// ---------------- host side ----------------
extern "C" void kernel_launch(void* const* d_in, const int* in_sizes, int n_in,
                              void* d_out, int out_size, void* d_ws, size_t ws_size,
                              hipStream_t stream) {
  const float* x  = (const float*)d_in[0];
  const int*   pos = (const int*)d_in[1];
  const float* Wq = (const float*)d_in[2];
  const float* Wk = (const float*)d_in[3];
  const float* Wv = (const float*)d_in[4];
  const float* Wo = (const float*)d_in[5];
  float* out = (float*)d_out;

  char* ws = (char*)d_ws;
  size_t off = 0;
  auto alloc = [&](size_t bytes) {
    void* p = ws + off;
    off += (bytes + 255) & ~(size_t)255;
    return p;
  };
  const size_t XB = (size_t)8192 * 1024 * 2;  // bf16 [B*S][D]
  u16* xb  = (u16*)alloc(XB);
  u16* wqb = (u16*)alloc((size_t)1024 * 1024 * 2);   // contiguous ->
  u16* wkb = (u16*)alloc((size_t)1024 * 1024 * 2);   //   Wcat[3072][1024] + wo
  u16* wvb = (u16*)alloc((size_t)1024 * 1024 * 2);
  u16* wob = (u16*)alloc((size_t)1024 * 1024 * 2);
  u16* qb  = (u16*)alloc(XB);                        // contiguous: q|k
  u16* kb  = (u16*)alloc(XB);
  u16* ob  = (u16*)alloc(XB);
  u16* vt  = (u16*)alloc(XB);
  float2* tab = (float2*)alloc((size_t)2048 * 32 * sizeof(float2));
  (void)wkb; (void)wvb;

  // merged prep: x convert + weight converts + rope table (one dispatch)
  k_prep<<<12544, 256, 0, stream>>>(x, Wq, Wk, Wv, Wo, pos, xb, wqb, tab);

  // fused QKV projection (BK=64 swizzled, dbuf, L2-supertile map); V -> vt
  k_gemm_qkv<<<1536, 256, 0, stream>>>(xb, wqb, qb, vt);

  // RoPE on K (in-place, vectorized); Q's RoPE happens inside attn
  k_rope_k<<<4096, 256, 0, stream>>>(kb, tab);

  // flash attention v14: 64 bh x 16 q-tiles of 128 rows, heavy-first
  k_attn14<<<1024, 256, 0, stream>>>(qb, kb, vt, tab, ob);

  // output projection -> f32 out, BK=64 swizzled, dbuf
  k_gemm_bt<<<512, 256, 0, stream>>>(ob, wob, out, 8192, 1024, 1024);
}

// Round 24
// 171.389 us; speedup vs baseline: 1.1507x; 1.0051x over previous
//
#include <hip/hip_runtime.h>

typedef unsigned short u16;
typedef __bf16 bf16x8 __attribute__((ext_vector_type(8)));
typedef float f32x4 __attribute__((ext_vector_type(4)));
typedef u16 u16x8 __attribute__((ext_vector_type(8)));

#define B_ 4
#define S_ 2048
#define D_ 1024
#define H_ 16
#define LOG2E 1.44269504f

__device__ inline u16 f2bf(float f) {
  unsigned u = __float_as_uint(f);
  u = u + 0x7fffu + ((u >> 16) & 1u);
  return (u16)(u >> 16);
}
__device__ inline u16 f2bf_hw(float f) {
  __bf16 b = (__bf16)f;
  return __builtin_bit_cast(u16, b);
}
__device__ inline float bf2f(u16 h) {
  return __uint_as_float(((unsigned)h) << 16);
}
__device__ inline void gload_lds16(const u16* g, u16* l) {
  __builtin_amdgcn_global_load_lds((const __attribute__((address_space(1))) void*)g,
                                   (__attribute__((address_space(3))) void*)l, 16, 0, 0);
}
// raw HW exp2: one TRANS op, no libm denormal fix-up (inputs bounded).
__device__ inline float fast_exp2(float x) {
  float r;
  asm("v_exp_f32 %0, %1" : "=v"(r) : "v"(x));
  return r;
}

// ---------------- merged prep: x convert | w4 convert | rope table -----------
__global__ __launch_bounds__(256) void k_prep(const float* __restrict__ x,
                                              const float* __restrict__ w0,
                                              const float* __restrict__ w1,
                                              const float* __restrict__ w2,
                                              const float* __restrict__ w3,
                                              const int* __restrict__ pos,
                                              u16* __restrict__ xb,
                                              u16* __restrict__ wdst,
                                              float2* __restrict__ tab) {
  const int bid = blockIdx.x;
  if (bid < 8192) {                      // x: 2097152 float4 groups
    int i = bid * 256 + threadIdx.x;
    float4 v = reinterpret_cast<const float4*>(x)[i];
    ushort4 o;
    o.x = f2bf(v.x); o.y = f2bf(v.y); o.z = f2bf(v.z); o.w = f2bf(v.w);
    reinterpret_cast<ushort4*>(xb)[i] = o;
  } else if (bid < 12288) {              // weights: 4 x 262144 float4 groups
    int i = (bid - 8192) * 256 + threadIdx.x;
    const int tensor = i >> 18;
    const int local = i & 262143;
    const float* s = tensor == 0 ? w0 : tensor == 1 ? w1 : tensor == 2 ? w2 : w3;
    float4 v = reinterpret_cast<const float4*>(s)[local];
    ushort4 o;
    o.x = f2bf(v.x); o.y = f2bf(v.y); o.z = f2bf(v.z); o.w = f2bf(v.w);
    reinterpret_cast<ushort4*>(wdst + (size_t)tensor * 1048576)[local] = o;
  } else {                               // rope table: S*32 entries
    int idx = (bid - 12288) * 256 + threadIdx.x;
    int s = idx >> 5, i = idx & 31;
    float freq = powf(10000.0f, -(float)i * (1.0f / 32.0f));  // precise powf
    float ang = (float)pos[s] * freq;
    float sn, c;
    sincosf(ang, &sn, &c);
    tab[idx] = make_float2(c, sn);
  }
}

// ---------------- RoPE on K, in-place, vectorized (8 elems = 4 pairs/thread) -
__global__ __launch_bounds__(256) void k_rope_k(u16* __restrict__ kb,
                                                const float2* __restrict__ tab) {
  int idx = blockIdx.x * 256 + threadIdx.x;      // 1M threads
  const int row = idx >> 7;                      // 0..8191 (b*2048+s)
  const int s = row & 2047;
  const int chunk = idx & 127;                   // 8-elem chunk within row
  u16* p = kb + ((size_t)row << 10) + chunk * 8;
  u16x8 v = *reinterpret_cast<u16x8*>(p);
  const float4* tp = reinterpret_cast<const float4*>(tab + s * 32 + (chunk & 7) * 4);
  float4 t0 = tp[0], t1 = tp[1];
  float cc[4] = {t0.x, t0.z, t1.x, t1.z};
  float ss[4] = {t0.y, t0.w, t1.y, t1.w};
  u16x8 o;
#pragma unroll
  for (int u = 0; u < 4; u++) {
    float x1 = bf2f(v[2 * u]), x2 = bf2f(v[2 * u + 1]);
    o[2 * u]     = f2bf(x1 * cc[u] - x2 * ss[u]);
    o[2 * u + 1] = f2bf(x1 * ss[u] + x2 * cc[u]);
  }
  *reinterpret_cast<u16x8*>(p) = o;
}

// ---------------- Fused QKV GEMM: BK=64 swizzled + dbuf + counted vmcnt ------
// L2-supertile block map (8m x 8n window = 4MB = per-XCD L2). launch_bounds
// min-waves/EU = 3: the residency cap was registers (120V+64A=184 > 512/3),
// not LDS; forcing <=170 unified regs lifts occupancy 2 -> 3 waves/SIMD.
__global__ __launch_bounds__(256, 3) void k_gemm_qkv(const u16* __restrict__ A,
                                                     const u16* __restrict__ Bcat,
                                                     u16* __restrict__ Ccat,
                                                     u16* __restrict__ Vt) {
  __shared__ u16 As[2][128 * 64];
  __shared__ u16 Bs[2][128 * 64];
  const int K = 1024;
  const int xcd = blockIdx.x & 7;
  const int idx = blockIdx.x >> 3;               // 0..191
  const int st = idx >> 6;                       // 0..2 supertile col (8 n each)
  const int mi = (idx & 63) >> 3;                // 0..7
  const int ni = idx & 7;                        // 0..7
  const int by = xcd * 8 + mi;                   // m-tile 0..63
  const int bx = st * 8 + ni;                    // n-tile 0..23
  const int m0 = by << 7, n0 = bx << 7;
  const int tid = threadIdx.x;
  const int lane = tid & 63;
  const int wv = tid >> 6;
  const int wm = (wv >> 1) << 6;
  const int wn = (wv & 1) << 6;
  const int r = lane & 15, g = lane >> 4;

  f32x4 acc[4][4] = {};

  const int srow0 = tid >> 3;
  const int scol = (((tid & 7) ^ ((tid >> 3) & 7)) * 8);
  const int csw = r & 7;

  const u16* Ab = A + (size_t)(m0 + srow0) * K + scol;
  const u16* Bb = Bcat + (size_t)(n0 + srow0) * K + scol;

#define STAGEQ(k0v, bf) do {                                       \
    const u16* a_ = Ab + (k0v);                                    \
    const u16* b_ = Bb + (k0v);                                    \
    gload_lds16(a_,                &As[bf][0] + tid * 8);          \
    gload_lds16(a_ + (size_t)32 * K, &As[bf][0] + tid * 8 + 2048); \
    gload_lds16(a_ + (size_t)64 * K, &As[bf][0] + tid * 8 + 4096); \
    gload_lds16(a_ + (size_t)96 * K, &As[bf][0] + tid * 8 + 6144); \
    gload_lds16(b_,                &Bs[bf][0] + tid * 8);          \
    gload_lds16(b_ + (size_t)32 * K, &Bs[bf][0] + tid * 8 + 2048); \
    gload_lds16(b_ + (size_t)64 * K, &Bs[bf][0] + tid * 8 + 4096); \
    gload_lds16(b_ + (size_t)96 * K, &Bs[bf][0] + tid * 8 + 6144); \
  } while (0)

  STAGEQ(0, 0);

  for (int t = 0; t < 16; ++t) {
    const int bsel = t & 1;
    if (t < 15) {
      STAGEQ((t + 1) * 64, bsel ^ 1);
      asm volatile("s_waitcnt vmcnt(8)" ::: "memory");   // current tile landed
    } else {
      asm volatile("s_waitcnt vmcnt(0)" ::: "memory");
    }
    __builtin_amdgcn_s_barrier();
    asm volatile("" ::: "memory");

#pragma unroll
    for (int ks = 0; ks < 2; ks++) {
      bf16x8 af[4], bfr[4];
#pragma unroll
      for (int i = 0; i < 4; i++)
        af[i] = *reinterpret_cast<const bf16x8*>(
            &As[bsel][(wm + i * 16 + r) * 64 + (((ks * 4 + g) ^ csw) * 8)]);
#pragma unroll
      for (int t2 = 0; t2 < 4; t2++)
        bfr[t2] = *reinterpret_cast<const bf16x8*>(
            &Bs[bsel][(wn + t2 * 16 + r) * 64 + (((ks * 4 + g) ^ csw) * 8)]);
#pragma unroll
      for (int i = 0; i < 4; i++)
#pragma unroll
        for (int t2 = 0; t2 < 4; t2++)
          acc[i][t2] = __builtin_amdgcn_mfma_f32_16x16x32_bf16(af[i], bfr[t2], acc[i][t2], 0, 0, 0);
    }
    asm volatile("" ::: "memory");
    __builtin_amdgcn_s_barrier();                        // reads of bsel done
  }
#undef STAGEQ

  const int bq = n0 >> 10;                 // 0=q, 1=k, 2=v
  const int c0 = n0 & 1023;
  if (bq == 2) {
    // V third -> vt[bh][d(64)][s(2048)]; j-values are consecutive s -> ushort4
#pragma unroll
    for (int i = 0; i < 4; i++) {
#pragma unroll
      for (int t = 0; t < 4; t++) {
        const int row = m0 + wm + i * 16 + g * 4;
        const int col = c0 + wn + t * 16 + r;
        const int b = row >> 11, s0 = row & 2047;
        const int h = col >> 6, d = col & 63;
        ushort4 o;
        o.x = f2bf(acc[i][t][0]); o.y = f2bf(acc[i][t][1]);
        o.z = f2bf(acc[i][t][2]); o.w = f2bf(acc[i][t][3]);
        *reinterpret_cast<ushort4*>(
            Vt + (((size_t)(b * 16 + h) * 64 + d) << 11) + s0) = o;
      }
    }
  } else {
    u16* Cb = Ccat + (size_t)bq * (8192 * 1024);
#pragma unroll
    for (int i = 0; i < 4; i++) {
#pragma unroll
      for (int t = 0; t < 4; t++) {
        const int row = m0 + wm + i * 16 + g * 4;
        const int col = c0 + wn + t * 16 + r;
#pragma unroll
        for (int j = 0; j < 4; j++)
          Cb[(size_t)(row + j) * 1024 + col] = f2bf(acc[i][t][j]);
      }
    }
  }
}

// ---------------- GEMM (f32 out, for Wo): BK=64 swizzled + dbuf --------------
__global__ __launch_bounds__(256, 3) void k_gemm_bt(const u16* __restrict__ A,
                                                    const u16* __restrict__ Bw,
                                                    float* __restrict__ C,
                                                    int M, int N, int K) {
  __shared__ u16 As[2][128 * 64];
  __shared__ u16 Bs[2][128 * 64];
  const int nbx = N >> 7;
  const int swz = (blockIdx.x & 7) * (gridDim.x >> 3) + (blockIdx.x >> 3);
  const int bx = swz % nbx;
  const int by = swz / nbx;
  const int m0 = by << 7, n0 = bx << 7;
  const int tid = threadIdx.x;
  const int lane = tid & 63;
  const int wv = tid >> 6;
  const int wm = (wv >> 1) << 6;
  const int wn = (wv & 1) << 6;
  const int r = lane & 15, g = lane >> 4;

  f32x4 acc[4][4] = {};

  const int srow0 = tid >> 3;
  const int scol = (((tid & 7) ^ ((tid >> 3) & 7)) * 8);
  const int csw = r & 7;

  const u16* Ab = A + (size_t)(m0 + srow0) * K + scol;
  const u16* Bb = Bw + (size_t)(n0 + srow0) * K + scol;
  const int nt = K >> 6;

#define STAGEW(k0v, bf) do {                                       \
    const u16* a_ = Ab + (k0v);                                    \
    const u16* b_ = Bb + (k0v);                                    \
    gload_lds16(a_,                &As[bf][0] + tid * 8);          \
    gload_lds16(a_ + (size_t)32 * K, &As[bf][0] + tid * 8 + 2048); \
    gload_lds16(a_ + (size_t)64 * K, &As[bf][0] + tid * 8 + 4096); \
    gload_lds16(a_ + (size_t)96 * K, &As[bf][0] + tid * 8 + 6144); \
    gload_lds16(b_,                &Bs[bf][0] + tid * 8);          \
    gload_lds16(b_ + (size_t)32 * K, &Bs[bf][0] + tid * 8 + 2048); \
    gload_lds16(b_ + (size_t)64 * K, &Bs[bf][0] + tid * 8 + 4096); \
    gload_lds16(b_ + (size_t)96 * K, &Bs[bf][0] + tid * 8 + 6144); \
  } while (0)

  STAGEW(0, 0);

  for (int t = 0; t < nt; ++t) {
    const int bsel = t & 1;
    if (t < nt - 1) {
      STAGEW((t + 1) * 64, bsel ^ 1);
      asm volatile("s_waitcnt vmcnt(8)" ::: "memory");
    } else {
      asm volatile("s_waitcnt vmcnt(0)" ::: "memory");
    }
    __builtin_amdgcn_s_barrier();
    asm volatile("" ::: "memory");

#pragma unroll
    for (int ks = 0; ks < 2; ks++) {
      bf16x8 af[4], bfr[4];
#pragma unroll
      for (int i = 0; i < 4; i++)
        af[i] = *reinterpret_cast<const bf16x8*>(
            &As[bsel][(wm + i * 16 + r) * 64 + (((ks * 4 + g) ^ csw) * 8)]);
#pragma unroll
      for (int t2 = 0; t2 < 4; t2++)
        bfr[t2] = *reinterpret_cast<const bf16x8*>(
            &Bs[bsel][(wn + t2 * 16 + r) * 64 + (((ks * 4 + g) ^ csw) * 8)]);
#pragma unroll
      for (int i = 0; i < 4; i++)
#pragma unroll
        for (int t2 = 0; t2 < 4; t2++)
          acc[i][t2] = __builtin_amdgcn_mfma_f32_16x16x32_bf16(af[i], bfr[t2], acc[i][t2], 0, 0, 0);
    }
    asm volatile("" ::: "memory");
    __builtin_amdgcn_s_barrier();
  }
#undef STAGEW

#pragma unroll
  for (int i = 0; i < 4; i++) {
#pragma unroll
    for (int t = 0; t < 4; t++) {
      const int row = m0 + wm + i * 16 + g * 4;
      const int col = n0 + wn + t * 16 + r;
#pragma unroll
      for (int j = 0; j < 4; j++)
        C[(size_t)(row + j) * N + col] = acc[i][t][j];
    }
  }
}

// ---------------- Flash attention v14 (measured-best) ------------------------
// fast_exp2 softmax; MFMA row-sum l; in-register Q-RoPE; single-buffer LDS.
__global__ __launch_bounds__(256) void k_attn14(const u16* __restrict__ Q,
                                                const u16* __restrict__ Kb,
                                                const u16* __restrict__ Vt,
                                                const float2* __restrict__ tab,
                                                u16* __restrict__ O) {
  __shared__ u16 Ks[64 * 64];       // [k(64)][d(64)] swizzled
  __shared__ u16 Vs[64 * 64];       // [d(64)][kv(64)] swizzled
  __shared__ u16 Ps[4][32 * 64];    // per-wave [q(32)][k(64)] swizzled

  const int bh = (blockIdx.x & 7) * 8 + ((blockIdx.x >> 3) & 7);
  const int qt = 15 - (blockIdx.x >> 6);
  const int b = bh >> 4, h = bh & 15;
  const int tid = threadIdx.x;
  const int lane = tid & 63, w = tid >> 6;
  const int g = lane >> 4, r = lane & 15;

  const u16* Kbase = Kb + (size_t)(b * S_) * 1024 + h * 64;
  const u16* Vbase = Vt + (size_t)bh * 64 * 2048;

  const int srow = tid >> 3;
  const int scol = ((tid & 7) * 8) ^ ((srow & 7) * 8);
  const int rsw = (r & 7) * 8;

  const int qbase = qt << 7;
  const int qrow0 = qbase + (w << 5);

  const float QSC = 0.125f * LOG2E;
  bf16x8 qf[2][2];
#pragma unroll
  for (int f = 0; f < 2; f++) {
    const int s = qrow0 + f * 16 + r;
    const u16* qrow = Q + (size_t)(b * S_ + s) * 1024 + h * 64;
    qf[f][0] = *reinterpret_cast<const bf16x8*>(qrow + g * 8);
    qf[f][1] = *reinterpret_cast<const bf16x8*>(qrow + 32 + g * 8);
    const float4* tp = reinterpret_cast<const float4*>(tab + s * 32);
#pragma unroll
    for (int c = 0; c < 2; c++) {
      float4 t0 = tp[c * 8 + g * 2], t1 = tp[c * 8 + g * 2 + 1];
      float cc[4] = {t0.x, t0.z, t1.x, t1.z};
      float ss[4] = {t0.y, t0.w, t1.y, t1.w};
      bf16x8 q = qf[f][c];
#pragma unroll
      for (int u = 0; u < 4; u++) {
        float x1 = (float)q[2 * u], x2 = (float)q[2 * u + 1];
        q[2 * u]     = (__bf16)((x1 * cc[u] - x2 * ss[u]) * QSC);
        q[2 * u + 1] = (__bf16)((x1 * ss[u] + x2 * cc[u]) * QSC);
      }
      qf[f][c] = q;
    }
  }

  // all-ones B fragment (layout-independent: every element 1.0bf16)
  bf16x8 ones;
#pragma unroll
  for (int u = 0; u < 8; u++) ones[u] = (__bf16)1.0f;

  f32x4 o_acc[2][4] = {};
  f32x4 lacc[2] = {};                  // MFMA row-sum accumulators
  u16* pb0 = &Ps[w][r * 64];
  u16* pb1 = &Ps[w][(16 + r) * 64];

  const u16* kp0 = Kbase + (size_t)srow * 1024 + scol;
  const u16* kp1 = kp0 + 32 * 1024;
  const u16* vp0 = Vbase + (size_t)srow * 2048 + scol;
  const u16* vp1 = vp0 + 32 * 2048;

  const int kend = qbase + 128;
  for (int k0 = 0; k0 < kend; k0 += 64) {
    gload_lds16(kp0, Ks + tid * 8);
    gload_lds16(kp1, Ks + tid * 8 + 2048);
    gload_lds16(vp0, Vs + tid * 8);
    gload_lds16(vp1, Vs + tid * 8 + 2048);
    kp0 += 64 * 1024; kp1 += 64 * 1024; vp0 += 64; vp1 += 64;
    __syncthreads();

    if (k0 <= qrow0 + 31) {
      const int rem0 = qrow0 + 15 - k0;
      const int rem1 = qrow0 + 31 - k0;
      const int ktlim0 = rem0 < 0 ? 0 : (rem0 >= 48 ? 4 : (rem0 >> 4) + 1);
      const int ktlim1 = rem1 >= 48 ? 4 : (rem1 >> 4) + 1;
      const bool mask0 = (k0 + 63 > qrow0);
      const bool mask1 = (k0 + 63 > qrow0 + 16);

#pragma unroll
      for (int kt = 0; kt < 4; kt++) {
        const int pc = (kt * 16 + g * 4) ^ rsw;
        if (kt >= ktlim1) {
          ushort4 z = {0, 0, 0, 0};
          *reinterpret_cast<ushort4*>(pb0 + pc) = z;
          *reinterpret_cast<ushort4*>(pb1 + pc) = z;
          continue;
        }
        const int krow = kt * 16 + r;
        bf16x8 kf0 = *reinterpret_cast<const bf16x8*>(&Ks[krow * 64 + ((g * 8) ^ rsw)]);
        bf16x8 kf1 = *reinterpret_cast<const bf16x8*>(&Ks[krow * 64 + ((32 + g * 8) ^ rsw)]);
        f32x4 s0 = {}, s1 = {};
        if (kt < ktlim0) {
          s0 = __builtin_amdgcn_mfma_f32_16x16x32_bf16(kf0, qf[0][0], s0, 0, 0, 0);
          s0 = __builtin_amdgcn_mfma_f32_16x16x32_bf16(kf1, qf[0][1], s0, 0, 0, 0);
        }
        s1 = __builtin_amdgcn_mfma_f32_16x16x32_bf16(kf0, qf[1][0], s1, 0, 0, 0);
        s1 = __builtin_amdgcn_mfma_f32_16x16x32_bf16(kf1, qf[1][1], s1, 0, 0, 0);

        const int colb = k0 + kt * 16 + g * 4;
        float p0[4], p1[4];
        if (kt < ktlim0) {
          if (mask0) {
#pragma unroll
            for (int j = 0; j < 4; j++)
              if (colb + j > qrow0 + r) s0[j] = -1e30f;
          }
#pragma unroll
          for (int j = 0; j < 4; j++) p0[j] = fast_exp2(s0[j]);
        } else {
#pragma unroll
          for (int j = 0; j < 4; j++) p0[j] = 0.f;
        }
        if (mask1) {
#pragma unroll
          for (int j = 0; j < 4; j++)
            if (colb + j > qrow0 + 16 + r) s1[j] = -1e30f;
        }
#pragma unroll
        for (int j = 0; j < 4; j++) p1[j] = fast_exp2(s1[j]);

        ushort4 w0, w1;
        w0.x = f2bf_hw(p0[0]); w0.y = f2bf_hw(p0[1]); w0.z = f2bf_hw(p0[2]); w0.w = f2bf_hw(p0[3]);
        w1.x = f2bf_hw(p1[0]); w1.y = f2bf_hw(p1[1]); w1.z = f2bf_hw(p1[2]); w1.w = f2bf_hw(p1[3]);
        *reinterpret_cast<ushort4*>(pb0 + pc) = w0;
        *reinterpret_cast<ushort4*>(pb1 + pc) = w1;
      }
      asm volatile("s_waitcnt lgkmcnt(0)" ::: "memory");

      // ---- PV + MFMA row-sum of P (l) ----
#pragma unroll
      for (int kc = 0; kc < 2; kc++) {
        const int cb = (kc * 32 + g * 8) ^ rsw;
        bf16x8 pf0 = *reinterpret_cast<const bf16x8*>(pb0 + cb);
        bf16x8 pf1 = *reinterpret_cast<const bf16x8*>(pb1 + cb);
        lacc[0] = __builtin_amdgcn_mfma_f32_16x16x32_bf16(pf0, ones, lacc[0], 0, 0, 0);
        lacc[1] = __builtin_amdgcn_mfma_f32_16x16x32_bf16(pf1, ones, lacc[1], 0, 0, 0);
#pragma unroll
        for (int dt = 0; dt < 4; dt++) {
          bf16x8 vf = *reinterpret_cast<const bf16x8*>(
              &Vs[(dt * 16 + r) * 64 + ((kc * 32 + g * 8) ^ rsw)]);
          o_acc[0][dt] = __builtin_amdgcn_mfma_f32_16x16x32_bf16(pf0, vf, o_acc[0][dt], 0, 0, 0);
          o_acc[1][dt] = __builtin_amdgcn_mfma_f32_16x16x32_bf16(pf1, vf, o_acc[1][dt], 0, 0, 0);
        }
      }
    }
    __syncthreads();
  }

  // ---- epilogue: lacc[f][j] IS l for output row g*4+j (no shuffles) ----
#pragma unroll
  for (int f = 0; f < 2; f++) {
    u16* orow = O + (size_t)(b * S_ + qrow0 + f * 16) * 1024 + h * 64;
#pragma unroll
    for (int j = 0; j < 4; j++) {
      const float rln = 1.0f / lacc[f][j];
#pragma unroll
      for (int dt = 0; dt < 4; dt++)
        orow[(size_t)(g * 4 + j) * 1024 + dt * 16 + r] = f2bf(o_acc[f][dt][j] * rln);
    }
  }
}

// ---------------- host side ----------------
extern "C" void kernel_launch(void* const* d_in, const int* in_sizes, int n_in,
                              void* d_out, int out_size, void* d_ws, size_t ws_size,
                              hipStream_t stream) {
  const float* x  = (const float*)d_in[0];
  const int*   pos = (const int*)d_in[1];
  const float* Wq = (const float*)d_in[2];
  const float* Wk = (const float*)d_in[3];
  const float* Wv = (const float*)d_in[4];
  const float* Wo = (const float*)d_in[5];
  float* out = (float*)d_out;

  char* ws = (char*)d_ws;
  size_t off = 0;
  auto alloc = [&](size_t bytes) {
    void* p = ws + off;
    off += (bytes + 255) & ~(size_t)255;
    return p;
  };
  const size_t XB = (size_t)8192 * 1024 * 2;  // bf16 [B*S][D]
  u16* xb  = (u16*)alloc(XB);
  u16* wqb = (u16*)alloc((size_t)1024 * 1024 * 2);   // contiguous ->
  u16* wkb = (u16*)alloc((size_t)1024 * 1024 * 2);   //   Wcat[3072][1024] + wo
  u16* wvb = (u16*)alloc((size_t)1024 * 1024 * 2);
  u16* wob = (u16*)alloc((size_t)1024 * 1024 * 2);
  u16* qb  = (u16*)alloc(XB);                        // contiguous: q|k
  u16* kb  = (u16*)alloc(XB);
  u16* ob  = (u16*)alloc(XB);
  u16* vt  = (u16*)alloc(XB);
  float2* tab = (float2*)alloc((size_t)2048 * 32 * sizeof(float2));
  (void)wkb; (void)wvb;

  // merged prep: x convert + weight converts + rope table (one dispatch)
  k_prep<<<12544, 256, 0, stream>>>(x, Wq, Wk, Wv, Wo, pos, xb, wqb, tab);

  // fused QKV projection (BK=64 swizzled, dbuf, L2-supertile map); V -> vt
  k_gemm_qkv<<<1536, 256, 0, stream>>>(xb, wqb, qb, vt);

  // RoPE on K (in-place, vectorized); Q's RoPE happens inside attn
  k_rope_k<<<4096, 256, 0, stream>>>(kb, tab);

  // flash attention v14: 64 bh x 16 q-tiles of 128 rows, heavy-first
  k_attn14<<<1024, 256, 0, stream>>>(qb, kb, vt, tab, ob);

  // output projection -> f32 out, BK=64 swizzled, dbuf
  k_gemm_bt<<<512, 256, 0, stream>>>(ob, wob, out, 8192, 1024, 1024);
}

// Round 25
// 167.115 us; speedup vs baseline: 1.1801x; 1.0256x over previous
//
#include <hip/hip_runtime.h>

typedef unsigned short u16;
typedef __bf16 bf16x8 __attribute__((ext_vector_type(8)));
typedef float f32x4 __attribute__((ext_vector_type(4)));
typedef u16 u16x8 __attribute__((ext_vector_type(8)));

#define B_ 4
#define S_ 2048
#define D_ 1024
#define H_ 16
#define LOG2E 1.44269504f

__device__ inline u16 f2bf(float f) {
  unsigned u = __float_as_uint(f);
  u = u + 0x7fffu + ((u >> 16) & 1u);
  return (u16)(u >> 16);
}
__device__ inline u16 f2bf_hw(float f) {
  __bf16 b = (__bf16)f;
  return __builtin_bit_cast(u16, b);
}
__device__ inline float bf2f(u16 h) {
  return __uint_as_float(((unsigned)h) << 16);
}
__device__ inline void gload_lds16(const u16* g, u16* l) {
  __builtin_amdgcn_global_load_lds((const __attribute__((address_space(1))) void*)g,
                                   (__attribute__((address_space(3))) void*)l, 16, 0, 0);
}
// raw HW exp2: one TRANS op, no libm denormal fix-up (inputs bounded).
__device__ inline float fast_exp2(float x) {
  float r;
  asm("v_exp_f32 %0, %1" : "=v"(r) : "v"(x));
  return r;
}

// ---------------- merged prep: x convert | w4 convert | rope table -----------
__global__ __launch_bounds__(256) void k_prep(const float* __restrict__ x,
                                              const float* __restrict__ w0,
                                              const float* __restrict__ w1,
                                              const float* __restrict__ w2,
                                              const float* __restrict__ w3,
                                              const int* __restrict__ pos,
                                              u16* __restrict__ xb,
                                              u16* __restrict__ wdst,
                                              float2* __restrict__ tab) {
  const int bid = blockIdx.x;
  if (bid < 8192) {                      // x: 2097152 float4 groups
    int i = bid * 256 + threadIdx.x;
    float4 v = reinterpret_cast<const float4*>(x)[i];
    ushort4 o;
    o.x = f2bf(v.x); o.y = f2bf(v.y); o.z = f2bf(v.z); o.w = f2bf(v.w);
    reinterpret_cast<ushort4*>(xb)[i] = o;
  } else if (bid < 12288) {              // weights: 4 x 262144 float4 groups
    int i = (bid - 8192) * 256 + threadIdx.x;
    const int tensor = i >> 18;
    const int local = i & 262143;
    const float* s = tensor == 0 ? w0 : tensor == 1 ? w1 : tensor == 2 ? w2 : w3;
    float4 v = reinterpret_cast<const float4*>(s)[local];
    ushort4 o;
    o.x = f2bf(v.x); o.y = f2bf(v.y); o.z = f2bf(v.z); o.w = f2bf(v.w);
    reinterpret_cast<ushort4*>(wdst + (size_t)tensor * 1048576)[local] = o;
  } else {                               // rope table: S*32 entries
    int idx = (bid - 12288) * 256 + threadIdx.x;
    int s = idx >> 5, i = idx & 31;
    float freq = powf(10000.0f, -(float)i * (1.0f / 32.0f));  // precise powf
    float ang = (float)pos[s] * freq;
    float sn, c;
    sincosf(ang, &sn, &c);
    tab[idx] = make_float2(c, sn);
  }
}

// ---------------- RoPE on K, in-place, vectorized (8 elems = 4 pairs/thread) -
__global__ __launch_bounds__(256) void k_rope_k(u16* __restrict__ kb,
                                                const float2* __restrict__ tab) {
  int idx = blockIdx.x * 256 + threadIdx.x;      // 1M threads
  const int row = idx >> 7;                      // 0..8191 (b*2048+s)
  const int s = row & 2047;
  const int chunk = idx & 127;                   // 8-elem chunk within row
  u16* p = kb + ((size_t)row << 10) + chunk * 8;
  u16x8 v = *reinterpret_cast<u16x8*>(p);
  const float4* tp = reinterpret_cast<const float4*>(tab + s * 32 + (chunk & 7) * 4);
  float4 t0 = tp[0], t1 = tp[1];
  float cc[4] = {t0.x, t0.z, t1.x, t1.z};
  float ss[4] = {t0.y, t0.w, t1.y, t1.w};
  u16x8 o;
#pragma unroll
  for (int u = 0; u < 4; u++) {
    float x1 = bf2f(v[2 * u]), x2 = bf2f(v[2 * u + 1]);
    o[2 * u]     = f2bf(x1 * cc[u] - x2 * ss[u]);
    o[2 * u + 1] = f2bf(x1 * ss[u] + x2 * cc[u]);
  }
  *reinterpret_cast<u16x8*>(p) = o;
}

// ---------------- q|k GEMM: 256x256 tile, 8 waves of 128x64, dbuf ------------
// Per-wave 128x64 output (acc[8][4]) halves B-reads/FLOP and doubles FLOP per
// barrier period vs the 128^2 structure. Grid 32m x 8n = 256 blocks = exactly
// 1 block/CU, zero tail. 128KB LDS (gfx950 allows 160KB). Same proven dbuf +
// counted vmcnt(8) + both-sides swizzle as the 128^2 kernel.
__global__ __launch_bounds__(512) void k_gemm_qk(const u16* __restrict__ A,
                                                 const u16* __restrict__ Bqk,
                                                 u16* __restrict__ Cqk) {
  __shared__ u16 As[2][256 * 64];   // 64KB
  __shared__ u16 Bs[2][256 * 64];   // 64KB
  const int K = 1024;
  const int xcd = blockIdx.x & 7;
  const int idx = blockIdx.x >> 3;               // 0..31
  const int by = xcd * 4 + (idx & 3);            // m-tile 0..31
  const int bx = idx >> 2;                       // n-tile 0..7
  const int m0 = by << 8, n0 = bx << 8;
  const int tid = threadIdx.x;
  const int lane = tid & 63, w = tid >> 6;
  const int wr = w >> 2, wc = w & 3;             // 2 rows x 4 cols of waves
  const int r = lane & 15, g = lane >> 4;

  f32x4 acc[8][4] = {};

  const int srow = tid >> 3;                     // 0..63 (+64,+128,+192)
  const int scol = (((tid & 7) ^ ((tid >> 3) & 7)) * 8);  // pre-swizzled src col
  const int csw = r & 7;                         // read-side swizzle

  const u16* Ab = A + (size_t)(m0 + srow) * K + scol;
  const u16* Bb = Bqk + (size_t)(n0 + srow) * K + scol;

#define STG(k0v, bf) do {                                                \
    gload_lds16(Ab + (k0v),                   &As[bf][0] + tid * 8);     \
    gload_lds16(Ab + (k0v) + (size_t)64 * K,  &As[bf][0] + tid * 8 + 4096);  \
    gload_lds16(Ab + (k0v) + (size_t)128 * K, &As[bf][0] + tid * 8 + 8192);  \
    gload_lds16(Ab + (k0v) + (size_t)192 * K, &As[bf][0] + tid * 8 + 12288); \
    gload_lds16(Bb + (k0v),                   &Bs[bf][0] + tid * 8);     \
    gload_lds16(Bb + (k0v) + (size_t)64 * K,  &Bs[bf][0] + tid * 8 + 4096);  \
    gload_lds16(Bb + (k0v) + (size_t)128 * K, &Bs[bf][0] + tid * 8 + 8192);  \
    gload_lds16(Bb + (k0v) + (size_t)192 * K, &Bs[bf][0] + tid * 8 + 12288); \
  } while (0)

  STG(0, 0);

  for (int t = 0; t < 16; ++t) {
    const int bsel = t & 1;
    if (t < 15) {
      STG((t + 1) * 64, bsel ^ 1);
      asm volatile("s_waitcnt vmcnt(8)" ::: "memory");   // current tile landed
    } else {
      asm volatile("s_waitcnt vmcnt(0)" ::: "memory");
    }
    __builtin_amdgcn_s_barrier();
    asm volatile("" ::: "memory");

    const u16* Ah = &As[bsel][(wr * 128) * 64];
    const u16* Bh = &Bs[bsel][(wc * 64) * 64];
#pragma unroll
    for (int ks = 0; ks < 2; ks++) {
      bf16x8 bfr[4];
#pragma unroll
      for (int t2 = 0; t2 < 4; t2++)
        bfr[t2] = *reinterpret_cast<const bf16x8*>(
            &Bh[(t2 * 16 + r) * 64 + (((ks * 4 + g) ^ csw) * 8)]);
#pragma unroll
      for (int i = 0; i < 8; i++) {
        bf16x8 af = *reinterpret_cast<const bf16x8*>(
            &Ah[(i * 16 + r) * 64 + (((ks * 4 + g) ^ csw) * 8)]);
#pragma unroll
        for (int t2 = 0; t2 < 4; t2++)
          acc[i][t2] = __builtin_amdgcn_mfma_f32_16x16x32_bf16(af, bfr[t2], acc[i][t2], 0, 0, 0);
      }
    }
    asm volatile("" ::: "memory");
    __builtin_amdgcn_s_barrier();                        // reads of bsel done
  }
#undef STG

  // epilogue: cols 0..1023 -> q, 1024..2047 -> k (qb,kb contiguous)
  u16* Cb = Cqk + (size_t)(n0 >> 10) * (8192 * 1024);
  const int c0 = n0 & 1023;
#pragma unroll
  for (int i = 0; i < 8; i++) {
#pragma unroll
    for (int t2 = 0; t2 < 4; t2++) {
      const int row = m0 + wr * 128 + i * 16 + g * 4;
      const int col = c0 + wc * 64 + t2 * 16 + r;
#pragma unroll
      for (int j = 0; j < 4; j++)
        Cb[(size_t)(row + j) * 1024 + col] = f2bf(acc[i][t2][j]);
    }
  }
}

// ---------------- V GEMM: 128^2 BK=64 swizzled + dbuf; writes vt layout ------
__global__ __launch_bounds__(256) void k_gemm_v(const u16* __restrict__ A,
                                                const u16* __restrict__ Bw,
                                                u16* __restrict__ Vt) {
  __shared__ u16 As[2][128 * 64];
  __shared__ u16 Bs[2][128 * 64];
  const int K = 1024;
  const int xcd = blockIdx.x & 7;
  const int idx = blockIdx.x >> 3;               // 0..63
  const int by = xcd * 8 + (idx & 7);            // m-tile 0..63
  const int bx = idx >> 3;                       // n-tile 0..7
  const int m0 = by << 7, n0 = bx << 7;
  const int tid = threadIdx.x;
  const int lane = tid & 63;
  const int wv = tid >> 6;
  const int wm = (wv >> 1) << 6;
  const int wn = (wv & 1) << 6;
  const int r = lane & 15, g = lane >> 4;

  f32x4 acc[4][4] = {};

  const int srow0 = tid >> 3;
  const int scol = (((tid & 7) ^ ((tid >> 3) & 7)) * 8);
  const int csw = r & 7;

  const u16* Ab = A + (size_t)(m0 + srow0) * K + scol;
  const u16* Bb = Bw + (size_t)(n0 + srow0) * K + scol;

#define STAGEV(k0v, bf) do {                                       \
    const u16* a_ = Ab + (k0v);                                    \
    const u16* b_ = Bb + (k0v);                                    \
    gload_lds16(a_,                &As[bf][0] + tid * 8);          \
    gload_lds16(a_ + (size_t)32 * K, &As[bf][0] + tid * 8 + 2048); \
    gload_lds16(a_ + (size_t)64 * K, &As[bf][0] + tid * 8 + 4096); \
    gload_lds16(a_ + (size_t)96 * K, &As[bf][0] + tid * 8 + 6144); \
    gload_lds16(b_,                &Bs[bf][0] + tid * 8);          \
    gload_lds16(b_ + (size_t)32 * K, &Bs[bf][0] + tid * 8 + 2048); \
    gload_lds16(b_ + (size_t)64 * K, &Bs[bf][0] + tid * 8 + 4096); \
    gload_lds16(b_ + (size_t)96 * K, &Bs[bf][0] + tid * 8 + 6144); \
  } while (0)

  STAGEV(0, 0);

  for (int t = 0; t < 16; ++t) {
    const int bsel = t & 1;
    if (t < 15) {
      STAGEV((t + 1) * 64, bsel ^ 1);
      asm volatile("s_waitcnt vmcnt(8)" ::: "memory");
    } else {
      asm volatile("s_waitcnt vmcnt(0)" ::: "memory");
    }
    __builtin_amdgcn_s_barrier();
    asm volatile("" ::: "memory");

#pragma unroll
    for (int ks = 0; ks < 2; ks++) {
      bf16x8 af[4], bfr[4];
#pragma unroll
      for (int i = 0; i < 4; i++)
        af[i] = *reinterpret_cast<const bf16x8*>(
            &As[bsel][(wm + i * 16 + r) * 64 + (((ks * 4 + g) ^ csw) * 8)]);
#pragma unroll
      for (int t2 = 0; t2 < 4; t2++)
        bfr[t2] = *reinterpret_cast<const bf16x8*>(
            &Bs[bsel][(wn + t2 * 16 + r) * 64 + (((ks * 4 + g) ^ csw) * 8)]);
#pragma unroll
      for (int i = 0; i < 4; i++)
#pragma unroll
        for (int t2 = 0; t2 < 4; t2++)
          acc[i][t2] = __builtin_amdgcn_mfma_f32_16x16x32_bf16(af[i], bfr[t2], acc[i][t2], 0, 0, 0);
    }
    asm volatile("" ::: "memory");
    __builtin_amdgcn_s_barrier();
  }
#undef STAGEV

  // V -> vt[bh][d(64)][s(2048)]; j-values are consecutive s -> ushort4
#pragma unroll
  for (int i = 0; i < 4; i++) {
#pragma unroll
    for (int t = 0; t < 4; t++) {
      const int row = m0 + wm + i * 16 + g * 4;
      const int col = n0 + wn + t * 16 + r;
      const int b = row >> 11, s0 = row & 2047;
      const int h = col >> 6, d = col & 63;
      ushort4 o;
      o.x = f2bf(acc[i][t][0]); o.y = f2bf(acc[i][t][1]);
      o.z = f2bf(acc[i][t][2]); o.w = f2bf(acc[i][t][3]);
      *reinterpret_cast<ushort4*>(
          Vt + (((size_t)(b * 16 + h) * 64 + d) << 11) + s0) = o;
    }
  }
}

// ---------------- GEMM (f32 out, for Wo): BK=64 swizzled + dbuf --------------
__global__ __launch_bounds__(256) void k_gemm_bt(const u16* __restrict__ A,
                                                 const u16* __restrict__ Bw,
                                                 float* __restrict__ C,
                                                 int M, int N, int K) {
  __shared__ u16 As[2][128 * 64];
  __shared__ u16 Bs[2][128 * 64];
  const int nbx = N >> 7;
  const int swz = (blockIdx.x & 7) * (gridDim.x >> 3) + (blockIdx.x >> 3);
  const int bx = swz % nbx;
  const int by = swz / nbx;
  const int m0 = by << 7, n0 = bx << 7;
  const int tid = threadIdx.x;
  const int lane = tid & 63;
  const int wv = tid >> 6;
  const int wm = (wv >> 1) << 6;
  const int wn = (wv & 1) << 6;
  const int r = lane & 15, g = lane >> 4;

  f32x4 acc[4][4] = {};

  const int srow0 = tid >> 3;
  const int scol = (((tid & 7) ^ ((tid >> 3) & 7)) * 8);
  const int csw = r & 7;

  const u16* Ab = A + (size_t)(m0 + srow0) * K + scol;
  const u16* Bb = Bw + (size_t)(n0 + srow0) * K + scol;
  const int nt = K >> 6;

#define STAGEW(k0v, bf) do {                                       \
    const u16* a_ = Ab + (k0v);                                    \
    const u16* b_ = Bb + (k0v);                                    \
    gload_lds16(a_,                &As[bf][0] + tid * 8);          \
    gload_lds16(a_ + (size_t)32 * K, &As[bf][0] + tid * 8 + 2048); \
    gload_lds16(a_ + (size_t)64 * K, &As[bf][0] + tid * 8 + 4096); \
    gload_lds16(a_ + (size_t)96 * K, &As[bf][0] + tid * 8 + 6144); \
    gload_lds16(b_,                &Bs[bf][0] + tid * 8);          \
    gload_lds16(b_ + (size_t)32 * K, &Bs[bf][0] + tid * 8 + 2048); \
    gload_lds16(b_ + (size_t)64 * K, &Bs[bf][0] + tid * 8 + 4096); \
    gload_lds16(b_ + (size_t)96 * K, &Bs[bf][0] + tid * 8 + 6144); \
  } while (0)

  STAGEW(0, 0);

  for (int t = 0; t < nt; ++t) {
    const int bsel = t & 1;
    if (t < nt - 1) {
      STAGEW((t + 1) * 64, bsel ^ 1);
      asm volatile("s_waitcnt vmcnt(8)" ::: "memory");
    } else {
      asm volatile("s_waitcnt vmcnt(0)" ::: "memory");
    }
    __builtin_amdgcn_s_barrier();
    asm volatile("" ::: "memory");

#pragma unroll
    for (int ks = 0; ks < 2; ks++) {
      bf16x8 af[4], bfr[4];
#pragma unroll
      for (int i = 0; i < 4; i++)
        af[i] = *reinterpret_cast<const bf16x8*>(
            &As[bsel][(wm + i * 16 + r) * 64 + (((ks * 4 + g) ^ csw) * 8)]);
#pragma unroll
      for (int t2 = 0; t2 < 4; t2++)
        bfr[t2] = *reinterpret_cast<const bf16x8*>(
            &Bs[bsel][(wn + t2 * 16 + r) * 64 + (((ks * 4 + g) ^ csw) * 8)]);
#pragma unroll
      for (int i = 0; i < 4; i++)
#pragma unroll
        for (int t2 = 0; t2 < 4; t2++)
          acc[i][t2] = __builtin_amdgcn_mfma_f32_16x16x32_bf16(af[i], bfr[t2], acc[i][t2], 0, 0, 0);
    }
    asm volatile("" ::: "memory");
    __builtin_amdgcn_s_barrier();
  }
#undef STAGEW

#pragma unroll
  for (int i = 0; i < 4; i++) {
#pragma unroll
    for (int t = 0; t < 4; t++) {
      const int row = m0 + wm + i * 16 + g * 4;
      const int col = n0 + wn + t * 16 + r;
#pragma unroll
      for (int j = 0; j < 4; j++)
        C[(size_t)(row + j) * N + col] = acc[i][t][j];
    }
  }
}

// ---------------- Flash attention v14 (measured-best) ------------------------
// fast_exp2 softmax; MFMA row-sum l; in-register Q-RoPE; single-buffer LDS.
__global__ __launch_bounds__(256) void k_attn14(const u16* __restrict__ Q,
                                                const u16* __restrict__ Kb,
                                                const u16* __restrict__ Vt,
                                                const float2* __restrict__ tab,
                                                u16* __restrict__ O) {
  __shared__ u16 Ks[64 * 64];       // [k(64)][d(64)] swizzled
  __shared__ u16 Vs[64 * 64];       // [d(64)][kv(64)] swizzled
  __shared__ u16 Ps[4][32 * 64];    // per-wave [q(32)][k(64)] swizzled

  const int bh = (blockIdx.x & 7) * 8 + ((blockIdx.x >> 3) & 7);
  const int qt = 15 - (blockIdx.x >> 6);
  const int b = bh >> 4, h = bh & 15;
  const int tid = threadIdx.x;
  const int lane = tid & 63, w = tid >> 6;
  const int g = lane >> 4, r = lane & 15;

  const u16* Kbase = Kb + (size_t)(b * S_) * 1024 + h * 64;
  const u16* Vbase = Vt + (size_t)bh * 64 * 2048;

  const int srow = tid >> 3;
  const int scol = ((tid & 7) * 8) ^ ((srow & 7) * 8);
  const int rsw = (r & 7) * 8;

  const int qbase = qt << 7;
  const int qrow0 = qbase + (w << 5);

  const float QSC = 0.125f * LOG2E;
  bf16x8 qf[2][2];
#pragma unroll
  for (int f = 0; f < 2; f++) {
    const int s = qrow0 + f * 16 + r;
    const u16* qrow = Q + (size_t)(b * S_ + s) * 1024 + h * 64;
    qf[f][0] = *reinterpret_cast<const bf16x8*>(qrow + g * 8);
    qf[f][1] = *reinterpret_cast<const bf16x8*>(qrow + 32 + g * 8);
    const float4* tp = reinterpret_cast<const float4*>(tab + s * 32);
#pragma unroll
    for (int c = 0; c < 2; c++) {
      float4 t0 = tp[c * 8 + g * 2], t1 = tp[c * 8 + g * 2 + 1];
      float cc[4] = {t0.x, t0.z, t1.x, t1.z};
      float ss[4] = {t0.y, t0.w, t1.y, t1.w};
      bf16x8 q = qf[f][c];
#pragma unroll
      for (int u = 0; u < 4; u++) {
        float x1 = (float)q[2 * u], x2 = (float)q[2 * u + 1];
        q[2 * u]     = (__bf16)((x1 * cc[u] - x2 * ss[u]) * QSC);
        q[2 * u + 1] = (__bf16)((x1 * ss[u] + x2 * cc[u]) * QSC);
      }
      qf[f][c] = q;
    }
  }

  // all-ones B fragment (layout-independent: every element 1.0bf16)
  bf16x8 ones;
#pragma unroll
  for (int u = 0; u < 8; u++) ones[u] = (__bf16)1.0f;

  f32x4 o_acc[2][4] = {};
  f32x4 lacc[2] = {};                  // MFMA row-sum accumulators
  u16* pb0 = &Ps[w][r * 64];
  u16* pb1 = &Ps[w][(16 + r) * 64];

  const u16* kp0 = Kbase + (size_t)srow * 1024 + scol;
  const u16* kp1 = kp0 + 32 * 1024;
  const u16* vp0 = Vbase + (size_t)srow * 2048 + scol;
  const u16* vp1 = vp0 + 32 * 2048;

  const int kend = qbase + 128;
  for (int k0 = 0; k0 < kend; k0 += 64) {
    gload_lds16(kp0, Ks + tid * 8);
    gload_lds16(kp1, Ks + tid * 8 + 2048);
    gload_lds16(vp0, Vs + tid * 8);
    gload_lds16(vp1, Vs + tid * 8 + 2048);
    kp0 += 64 * 1024; kp1 += 64 * 1024; vp0 += 64; vp1 += 64;
    __syncthreads();

    if (k0 <= qrow0 + 31) {
      const int rem0 = qrow0 + 15 - k0;
      const int rem1 = qrow0 + 31 - k0;
      const int ktlim0 = rem0 < 0 ? 0 : (rem0 >= 48 ? 4 : (rem0 >> 4) + 1);
      const int ktlim1 = rem1 >= 48 ? 4 : (rem1 >> 4) + 1;
      const bool mask0 = (k0 + 63 > qrow0);
      const bool mask1 = (k0 + 63 > qrow0 + 16);

#pragma unroll
      for (int kt = 0; kt < 4; kt++) {
        const int pc = (kt * 16 + g * 4) ^ rsw;
        if (kt >= ktlim1) {
          ushort4 z = {0, 0, 0, 0};
          *reinterpret_cast<ushort4*>(pb0 + pc) = z;
          *reinterpret_cast<ushort4*>(pb1 + pc) = z;
          continue;
        }
        const int krow = kt * 16 + r;
        bf16x8 kf0 = *reinterpret_cast<const bf16x8*>(&Ks[krow * 64 + ((g * 8) ^ rsw)]);
        bf16x8 kf1 = *reinterpret_cast<const bf16x8*>(&Ks[krow * 64 + ((32 + g * 8) ^ rsw)]);
        f32x4 s0 = {}, s1 = {};
        if (kt < ktlim0) {
          s0 = __builtin_amdgcn_mfma_f32_16x16x32_bf16(kf0, qf[0][0], s0, 0, 0, 0);
          s0 = __builtin_amdgcn_mfma_f32_16x16x32_bf16(kf1, qf[0][1], s0, 0, 0, 0);
        }
        s1 = __builtin_amdgcn_mfma_f32_16x16x32_bf16(kf0, qf[1][0], s1, 0, 0, 0);
        s1 = __builtin_amdgcn_mfma_f32_16x16x32_bf16(kf1, qf[1][1], s1, 0, 0, 0);

        const int colb = k0 + kt * 16 + g * 4;
        float p0[4], p1[4];
        if (kt < ktlim0) {
          if (mask0) {
#pragma unroll
            for (int j = 0; j < 4; j++)
              if (colb + j > qrow0 + r) s0[j] = -1e30f;
          }
#pragma unroll
          for (int j = 0; j < 4; j++) p0[j] = fast_exp2(s0[j]);
        } else {
#pragma unroll
          for (int j = 0; j < 4; j++) p0[j] = 0.f;
        }
        if (mask1) {
#pragma unroll
          for (int j = 0; j < 4; j++)
            if (colb + j > qrow0 + 16 + r) s1[j] = -1e30f;
        }
#pragma unroll
        for (int j = 0; j < 4; j++) p1[j] = fast_exp2(s1[j]);

        ushort4 w0, w1;
        w0.x = f2bf_hw(p0[0]); w0.y = f2bf_hw(p0[1]); w0.z = f2bf_hw(p0[2]); w0.w = f2bf_hw(p0[3]);
        w1.x = f2bf_hw(p1[0]); w1.y = f2bf_hw(p1[1]); w1.z = f2bf_hw(p1[2]); w1.w = f2bf_hw(p1[3]);
        *reinterpret_cast<ushort4*>(pb0 + pc) = w0;
        *reinterpret_cast<ushort4*>(pb1 + pc) = w1;
      }
      asm volatile("s_waitcnt lgkmcnt(0)" ::: "memory");

      // ---- PV + MFMA row-sum of P (l) ----
#pragma unroll
      for (int kc = 0; kc < 2; kc++) {
        const int cb = (kc * 32 + g * 8) ^ rsw;
        bf16x8 pf0 = *reinterpret_cast<const bf16x8*>(pb0 + cb);
        bf16x8 pf1 = *reinterpret_cast<const bf16x8*>(pb1 + cb);
        lacc[0] = __builtin_amdgcn_mfma_f32_16x16x32_bf16(pf0, ones, lacc[0], 0, 0, 0);
        lacc[1] = __builtin_amdgcn_mfma_f32_16x16x32_bf16(pf1, ones, lacc[1], 0, 0, 0);
#pragma unroll
        for (int dt = 0; dt < 4; dt++) {
          bf16x8 vf = *reinterpret_cast<const bf16x8*>(
              &Vs[(dt * 16 + r) * 64 + ((kc * 32 + g * 8) ^ rsw)]);
          o_acc[0][dt] = __builtin_amdgcn_mfma_f32_16x16x32_bf16(pf0, vf, o_acc[0][dt], 0, 0, 0);
          o_acc[1][dt] = __builtin_amdgcn_mfma_f32_16x16x32_bf16(pf1, vf, o_acc[1][dt], 0, 0, 0);
        }
      }
    }
    __syncthreads();
  }

  // ---- epilogue: lacc[f][j] IS l for output row g*4+j (no shuffles) ----
#pragma unroll
  for (int f = 0; f < 2; f++) {
    u16* orow = O + (size_t)(b * S_ + qrow0 + f * 16) * 1024 + h * 64;
#pragma unroll
    for (int j = 0; j < 4; j++) {
      const float rln = 1.0f / lacc[f][j];
#pragma unroll
      for (int dt = 0; dt < 4; dt++)
        orow[(size_t)(g * 4 + j) * 1024 + dt * 16 + r] = f2bf(o_acc[f][dt][j] * rln);
    }
  }
}

// ---------------- host side ----------------
extern "C" void kernel_launch(void* const* d_in, const int* in_sizes, int n_in,
                              void* d_out, int out_size, void* d_ws, size_t ws_size,
                              hipStream_t stream) {
  const float* x  = (const float*)d_in[0];
  const int*   pos = (const int*)d_in[1];
  const float* Wq = (const float*)d_in[2];
  const float* Wk = (const float*)d_in[3];
  const float* Wv = (const float*)d_in[4];
  const float* Wo = (const float*)d_in[5];
  float* out = (float*)d_out;

  char* ws = (char*)d_ws;
  size_t off = 0;
  auto alloc = [&](size_t bytes) {
    void* p = ws + off;
    off += (bytes + 255) & ~(size_t)255;
    return p;
  };
  const size_t XB = (size_t)8192 * 1024 * 2;  // bf16 [B*S][D]
  u16* xb  = (u16*)alloc(XB);
  u16* wqb = (u16*)alloc((size_t)1024 * 1024 * 2);   // contiguous ->
  u16* wkb = (u16*)alloc((size_t)1024 * 1024 * 2);   //   Wcat[3072][1024] + wo
  u16* wvb = (u16*)alloc((size_t)1024 * 1024 * 2);
  u16* wob = (u16*)alloc((size_t)1024 * 1024 * 2);
  u16* qb  = (u16*)alloc(XB);                        // contiguous: q|k
  u16* kb  = (u16*)alloc(XB);
  u16* ob  = (u16*)alloc(XB);
  u16* vt  = (u16*)alloc(XB);
  float2* tab = (float2*)alloc((size_t)2048 * 32 * sizeof(float2));
  (void)wkb;

  // merged prep: x convert + weight converts + rope table (one dispatch)
  k_prep<<<12544, 256, 0, stream>>>(x, Wq, Wk, Wv, Wo, pos, xb, wqb, tab);

  // q|k projection: 256^2 tile, 8 waves, grid 256 = 1 block/CU, zero tail
  k_gemm_qk<<<256, 512, 0, stream>>>(xb, wqb, qb);

  // V projection: 128^2 dbuf, writes vt layout directly
  k_gemm_v<<<512, 256, 0, stream>>>(xb, wvb, vt);

  // RoPE on K (in-place, vectorized); Q's RoPE happens inside attn
  k_rope_k<<<4096, 256, 0, stream>>>(kb, tab);

  // flash attention v14: 64 bh x 16 q-tiles of 128 rows, heavy-first
  k_attn14<<<1024, 256, 0, stream>>>(qb, kb, vt, tab, ob);

  // output projection -> f32 out, BK=64 swizzled, dbuf
  k_gemm_bt<<<512, 256, 0, stream>>>(ob, wob, out, 8192, 1024, 1024);
}